// Round 16
// baseline (792.930 us; speedup 1.0000x reference)
//
#include <hip/hip_runtime.h>

typedef __attribute__((ext_vector_type(8))) short short8;
typedef __attribute__((ext_vector_type(4))) short short4v;
typedef __attribute__((ext_vector_type(4))) float floatx4;

__device__ __forceinline__ float b2f(short b) {
  union { unsigned u; float f; } v; v.u = ((unsigned)(unsigned short)b) << 16; return v.f;
}
__device__ __forceinline__ short f2b(float f) {
  union { float f; unsigned u; } v; v.f = f;
  return (short)((v.u + 0x7fffu + ((v.u >> 16) & 1u)) >> 16);
}
// packed f32x2 -> bf16x2 (RNE), single VOP3 instr
__device__ __forceinline__ unsigned cvtpk(float lo, float hi) {
  unsigned r;
  asm("v_cvt_pk_bf16_f32 %0, %1, %2" : "=v"(r) : "v"(lo), "v"(hi));
  return r;
}
__device__ __forceinline__ float loadf(const void* p, size_t i, bool f32) {
  return f32 ? ((const float*)p)[i] : b2f(((const short*)p)[i]);
}
__device__ __forceinline__ short8 load8(const void* p, size_t i, bool f32) {
  if (f32) {
    const float* fp = (const float*)p + i;
    float4 a = *(const float4*)fp;
    float4 b = *(const float4*)(fp + 4);
    short8 r;
    r[0] = f2b(a.x); r[1] = f2b(a.y); r[2] = f2b(a.z); r[3] = f2b(a.w);
    r[4] = f2b(b.x); r[5] = f2b(b.y); r[6] = f2b(b.z); r[7] = f2b(b.w);
    return r;
  }
  return *(const short8*)((const short*)p + i);
}

// async global->LDS, 16B per lane. LDS dest = wave-uniform base + lane*16.
__device__ __forceinline__ void gload16(const short* g, short* l) {
  __builtin_amdgcn_global_load_lds(
      (const __attribute__((address_space(1))) unsigned int*)g,
      (__attribute__((address_space(3))) unsigned int*)l, 16, 0, 0);
}

// ---------- dtype detector
__global__ void detect_dtype(const unsigned short* __restrict__ w, int* __restrict__ flag) {
  __shared__ int cnt;
  if (threadIdx.x == 0) cnt = 0;
  __syncthreads();
  int bad = 0;
  for (int i = threadIdx.x; i < 4096; i += 256) {
    int e = (w[i] >> 7) & 0xFF;
    if (e >= 0xC8) bad++;
  }
  atomicAdd(&cnt, bad);
  __syncthreads();
  if (threadIdx.x == 0) *flag = (cnt > 64) ? 1 : 0;
}

// ---------- one-time dtype normalization: two sources -> one contiguous dst
__global__ __launch_bounds__(256)
void cvt_bf16_2(const void* __restrict__ srcA, long n8A,
                const void* __restrict__ srcB, long n8B,
                short* __restrict__ dst, const int* __restrict__ dflag) {
  const bool f32 = (*dflag != 0);
  const long n8 = n8A + n8B;
  long stride = (long)gridDim.x * 256;
  for (long i = (long)blockIdx.x * 256 + threadIdx.x; i < n8; i += stride) {
    const void* s; long e;
    if (i < n8A) { s = srcA; e = i * 8; } else { s = srcB; e = (i - n8A) * 8; }
    if (f32) {
      const float* fp = (const float*)s + e;
      float4 a = *(const float4*)fp;
      float4 b = *(const float4*)(fp + 4);
      short8 r;
      r[0] = f2b(a.x); r[1] = f2b(a.y); r[2] = f2b(a.z); r[3] = f2b(a.w);
      r[4] = f2b(b.x); r[5] = f2b(b.y); r[6] = f2b(b.z); r[7] = f2b(b.w);
      *(short8*)(dst + i * 8) = r;
    } else {
      *(short8*)(dst + i * 8) = *(const short8*)((const short*)s + e);
    }
  }
}

// ---------- cvt_tw: all 4 weight transposes in ONE launch (1-D grid decode).
__global__ __launch_bounds__(256)
void cvt_tw(const void* __restrict__ wq, short* __restrict__ wqd,
            const void* __restrict__ waq, short* __restrict__ waqd,
            const void* __restrict__ wo, short* __restrict__ wod,
            const void* __restrict__ wao, short* __restrict__ waod,
            const int* __restrict__ dflag) {
  __shared__ short st[64][72];
  const bool f32 = (*dflag != 0);
  const int K = 3072;
  int b = blockIdx.x;
  const void* src; short* dst; int N, n0, k0;
  if (b < 13824) {               // two big matrices: 2 x (144 x 48)
    src = (b < 6912) ? wq : waq;
    dst = (b < 6912) ? wqd : waqd;
    int rem = b % 6912;
    N = 9216; n0 = (rem % 144) << 6; k0 = (rem / 144) << 6;
  } else {                       // two small: 2 x (48 x 48)
    b -= 13824;
    src = (b < 2304) ? wo : wao;
    dst = (b < 2304) ? wod : waod;
    int rem = b % 2304;
    N = 3072; n0 = (rem % 48) << 6; k0 = (rem / 48) << 6;
  }
  const int c4 = threadIdx.x & 15;
  const int rq = threadIdx.x >> 4;
#pragma unroll
  for (int r = 0; r < 4; ++r) {
    int k = r * 16 + rq;
    int n = c4 * 4;
    short v0, v1, v2, v3;
    if (f32) {
      const float* sp = (const float*)src + (size_t)(k0 + k) * N + n0 + n;
      float4 f = *(const float4*)sp;
      v0 = f2b(f.x); v1 = f2b(f.y); v2 = f2b(f.z); v3 = f2b(f.w);
    } else {
      const short* sp = (const short*)src + (size_t)(k0 + k) * N + n0 + n;
      short4v s = *(const short4v*)sp;
      v0 = s[0]; v1 = s[1]; v2 = s[2]; v3 = s[3];
    }
    st[n + 0][k] = v0; st[n + 1][k] = v1; st[n + 2][k] = v2; st[n + 3][k] = v3;
  }
  __syncthreads();
  const int n = threadIdx.x >> 2;
  const int kc = (threadIdx.x & 3) << 4;
  short8 a = *(const short8*)(&st[n][kc]);
  short8 bb = *(const short8*)(&st[n][kc + 8]);
  short* dp = dst + (size_t)(n0 + n) * K + k0 + kc;
  *(short8*)(dp) = a;
  *(short8*)(dp + 8) = bb;
}

// ---------- OLD GEMM (fallback) ----------
__global__ __launch_bounds__(256, 2)
void gemm_bt(const void* __restrict__ A, int a_row0,
             const void* __restrict__ B, const void* __restrict__ bias,
             void* __restrict__ C, int c_row0, int N, int K,
             const int* __restrict__ dflag, int aIn, int cOut) {
  __shared__ short As[128 * 32];
  __shared__ short Bs[128 * 32];
  const bool f32 = (*dflag != 0);
  const bool a32 = aIn && f32;
  const bool c32 = cOut && f32;
  const int tid = threadIdx.x;
  const int lane = tid & 63, w = tid >> 6;
  const int wm = w & 1, wn = w >> 1;
  const int qg = lane >> 4, l16 = lane & 15;
  const int m0 = blockIdx.y << 7, n0 = blockIdx.x << 7;

  const int arow = tid >> 2, ak = (tid & 3) << 3;
  const int brow = tid >> 4, bc = (tid & 15) << 3;
  const int rot = tid & 15;

  floatx4 acc[4][4];
#pragma unroll
  for (int i = 0; i < 4; ++i)
#pragma unroll
    for (int j = 0; j < 4; ++j) acc[i][j] = (floatx4){0.f, 0.f, 0.f, 0.f};

  for (int k0 = 0; k0 < K; k0 += 32) {
    __syncthreads();
#pragma unroll
    for (int j = 0; j < 2; ++j) {
      short8 av = load8(A, (size_t)(a_row0 + m0 + j * 64 + arow) * K + (k0 + ak), a32);
      *(short8*)(As + (j * 64 + arow) * 32 + ak) = av;
      int kr = j * 16 + brow;
      short8 bv = load8(B, (size_t)(k0 + kr) * N + (n0 + bc), f32);
      int kq = kr >> 3, kj = kr & 7;
#pragma unroll
      for (int s = 0; s < 8; ++s) {
        int u = (s + rot) & 7;
        int n = bc + u;
        Bs[(n << 5) + ((kq ^ (n & 3)) << 3) + kj] = bv[u];
      }
    }
    __syncthreads();
    short8 a[4];
#pragma unroll
    for (int mi = 0; mi < 4; ++mi)
      a[mi] = *(const short8*)(As + (wm * 64 + mi * 16 + l16) * 32 + qg * 8);
#pragma unroll
    for (int ni = 0; ni < 4; ++ni) {
      int n = wn * 64 + ni * 16 + l16;
      short8 b = *(const short8*)(Bs + (n << 5) + ((qg ^ (n & 3)) << 3));
#pragma unroll
      for (int mi = 0; mi < 4; ++mi)
        acc[mi][ni] = __builtin_amdgcn_mfma_f32_16x16x32_bf16(a[mi], b, acc[mi][ni], 0, 0, 0);
    }
  }
#pragma unroll
  for (int ni = 0; ni < 4; ++ni) {
    int col = n0 + wn * 64 + ni * 16 + l16;
    float bv = bias ? loadf(bias, col, f32) : 0.0f;
#pragma unroll
    for (int mi = 0; mi < 4; ++mi) {
      int row = m0 + wm * 64 + mi * 16 + qg * 4;
#pragma unroll
      for (int r = 0; r < 4; ++r) {
        size_t idx = (size_t)(c_row0 + row + r) * N + col;
        float val = acc[mi][ni][r] + bv;
        if (c32) ((float*)C)[idx] = val;
        else     ((short*)C)[idx] = f2b(val);
      }
    }
  }
}

// ---------- GEMM v11: 256x128 block tile, 128x64 WAVE tile.
// R15 diagnosis: 64x64 wave tile is LDS-read-throughput-bound (8 b128 reads
// per 16 MFMAs; 96 reads/CU-iter x ~12cyc ~= 1150cyc vs 310cyc MFMA need).
// 128x64 wave tile: 12 reads per 32 MFMAs (2.67 MFMA/read) -> LDS ~1150 and
// MFMA ~1230 cyc/CU-iter balanced at 1.33x FLOP throughput.
// Keeps: depth-2 pipeline, single barrier/K-step, counted vmcnt (6 gloads/
// STAGE -> vmcnt(6)), same swizzles, coalesced LDS-transposed epilogue
// (two 64-row halves through wave-private slice). LDS 72 KB -> 2 blocks/CU.
// Row tiles are 256 now: y-mapping uses (y<<8).
__global__ __launch_bounds__(256, 2)
void gemm_bf2(const short* __restrict__ A,
              const short* __restrict__ BTa, const void* __restrict__ biasa,
              int a0a, int c0a, int nYa,
              const short* __restrict__ BTb, const void* __restrict__ biasb,
              int a0b, int c0b,
              void* __restrict__ C, int N, int K,
              const int* __restrict__ dflag, int cOut) {
  __shared__ short Ls[3 * 8192 + 3 * 4096];    // 72 KB: 3 A bufs (256x32) + 3 B bufs (128x32)
#define ASB(b) (Ls + (b) * 8192)
#define BSB(b) (Ls + 24576 + (b) * 4096)
  const bool f32 = (*dflag != 0);
  const bool c32 = cOut && f32;
  const int bx = blockIdx.x;
  const int y = blockIdx.y;
  const short* BT; const void* bias; int arow0, crow0;
  if (y < nYa) { BT = BTa; bias = biasa; arow0 = a0a + (y << 8); crow0 = c0a + (y << 8); }
  else { int my = y - nYa; BT = BTb; bias = biasb; arow0 = a0b + (my << 8); crow0 = c0b + (my << 8); }
  const int tid = threadIdx.x;
  const int lane = tid & 63, w = tid >> 6;
  const int wm = w & 1, wn = w >> 1;          // wave tile: rows wm*128, cols wn*64
  const int qg = lane >> 4, l16 = lane & 15;
  const int n0 = bx << 7;
  const int garow = lane >> 2;
  const int gcir = lane & 3;
  const int nk = K >> 5;
  const int swz = (gcir ^ (garow & 3) ^ (garow >> 2)) << 3;
  const short* Abase = A + (size_t)(arow0 + w * 64 + garow) * K + swz;   // wave stages 64 A rows
  const short* Bbase = BT + (size_t)(n0 + w * 32 + garow) * K + swz;     // wave stages 32 B rows
  const int rswz = (l16 & 3) ^ (l16 >> 2);

  floatx4 acc[8][4];
#pragma unroll
  for (int i = 0; i < 8; ++i)
#pragma unroll
    for (int j = 0; j < 4; ++j) acc[i][j] = (floatx4){0.f, 0.f, 0.f, 0.f};

  auto STAGE = [&](int buf, int k0) {
#pragma unroll
    for (int j = 0; j < 4; ++j)
      gload16(Abase + (size_t)j * 16 * K + k0, ASB(buf) + ((w * 4 + j) << 9));
#pragma unroll
    for (int j = 0; j < 2; ++j)
      gload16(Bbase + (size_t)j * 16 * K + k0, BSB(buf) + ((w * 2 + j) << 9));
  };

  STAGE(0, 0);
  if (nk > 1) STAGE(1, 32);

  int cb = 0;
  for (int t = 0; t < nk; ++t) {
    if (t + 1 < nk) {
      asm volatile("s_waitcnt vmcnt(6) lgkmcnt(0)" ::: "memory");
    } else {
      asm volatile("s_waitcnt vmcnt(0) lgkmcnt(0)" ::: "memory");
    }
    __builtin_amdgcn_s_barrier();
    if (t + 2 < nk) {
      int sb = (cb == 0) ? 2 : cb - 1;   // (t+2)%3 == (t-1)%3
      STAGE(sb, (t + 2) << 5);
    }
    short8 a[8], b[4];
#pragma unroll
    for (int mi = 0; mi < 8; ++mi) {
      int ra = wm * 128 + mi * 16 + l16;
      a[mi] = *(const short8*)(ASB(cb) + (ra << 5) + ((qg ^ rswz) << 3));
    }
#pragma unroll
    for (int ni = 0; ni < 4; ++ni) {
      int n = wn * 64 + ni * 16 + l16;
      b[ni] = *(const short8*)(BSB(cb) + (n << 5) + ((qg ^ rswz) << 3));
    }
    __builtin_amdgcn_s_setprio(1);
#pragma unroll
    for (int ni = 0; ni < 4; ++ni)
#pragma unroll
      for (int mi = 0; mi < 8; ++mi)
        acc[mi][ni] = __builtin_amdgcn_mfma_f32_16x16x32_bf16(a[mi], b[ni], acc[mi][ni], 0, 0, 0);
    __builtin_amdgcn_s_setprio(0);
    cb = (cb == 2) ? 0 : cb + 1;
  }
  // ---- coalesced epilogue: two 64-row halves, each transposed through the
  // wave's PRIVATE 8KB LDS slice, vector stores.
  __builtin_amdgcn_s_barrier();   // all waves past final MFMA -> ds_reads retired
  if (!c32) {
    short* wreg = Ls + w * 4096;  // 64x64 shorts
#pragma unroll
    for (int half = 0; half < 2; ++half) {
#pragma unroll
      for (int ni = 0; ni < 4; ++ni) {
        float bvv = bias ? loadf(bias, n0 + wn * 64 + ni * 16 + l16, f32) : 0.0f;
#pragma unroll
        for (int mi2 = 0; mi2 < 4; ++mi2)
#pragma unroll
          for (int r = 0; r < 4; ++r)
            wreg[(mi2 * 16 + qg * 4 + r) * 64 + ni * 16 + l16] =
                f2b(acc[half * 4 + mi2][ni][r] + bvv);
      }
      asm volatile("s_waitcnt lgkmcnt(0)" ::: "memory");
#pragma unroll
      for (int j = 0; j < 8; ++j) {
        int row = j * 8 + (lane >> 3);
        int col = (lane & 7) * 8;
        short8 v = *(const short8*)(wreg + row * 64 + col);
        *(short8*)((short*)C + (size_t)(crow0 + wm * 128 + half * 64 + row) * N +
                   n0 + wn * 64 + col) = v;
      }
      asm volatile("s_waitcnt lgkmcnt(0)" ::: "memory");  // reads done before overwrite
    }
  } else {
    float* wregf = (float*)(Ls) + w * 2048;  // 64x32 floats
#pragma unroll
    for (int half = 0; half < 2; ++half) {
#pragma unroll
      for (int ch = 0; ch < 2; ++ch) {
#pragma unroll
        for (int nh = 0; nh < 2; ++nh) {
          int ni = ch * 2 + nh;
          float bvv = bias ? loadf(bias, n0 + wn * 64 + ni * 16 + l16, f32) : 0.0f;
#pragma unroll
          for (int mi2 = 0; mi2 < 4; ++mi2)
#pragma unroll
            for (int r = 0; r < 4; ++r)
              wregf[(mi2 * 16 + qg * 4 + r) * 32 + nh * 16 + l16] =
                  acc[half * 4 + mi2][ni][r] + bvv;
        }
        asm volatile("s_waitcnt lgkmcnt(0)" ::: "memory");
#pragma unroll
        for (int j = 0; j < 8; ++j) {
          int row = j * 8 + (lane >> 3);
          int c4 = (lane & 7) * 4;
          float4 v = *(const float4*)(wregf + row * 32 + c4);
          *(float4*)((float*)C + (size_t)(crow0 + wm * 128 + half * 64 + row) * N +
                     n0 + wn * 64 + ch * 32 + c4) = v;
        }
        asm volatile("s_waitcnt lgkmcnt(0)" ::: "memory");
      }
    }
  }
#undef ASB
#undef BSB
}

// ---------- RMSNorm + RoPE: one wave per head; q scaled by rsqrt(128)*log2(e).
__global__ __launch_bounds__(512)
void norm_rope(short* __restrict__ qkv, const int* __restrict__ ids,
               const void* __restrict__ nqw, const void* __restrict__ nkw,
               const void* __restrict__ naqw, const void* __restrict__ nakw,
               const int* __restrict__ dflag) {
  const bool f32 = (*dflag != 0);
  const int t = blockIdx.x, wv = threadIdx.x >> 6, lane = threadIdx.x & 63;
  const bool txt = t < 512;
  int p = lane, axis; float expo;
  if (p < 8)       { axis = 0; expo = (float)(2 * p) * (1.0f / 16.0f); }
  else if (p < 36) { axis = 1; expo = (float)(2 * (p - 8)) * (1.0f / 56.0f); }
  else             { axis = 2; expo = (float)(2 * (p - 36)) * (1.0f / 56.0f); }
  float freq = __expf(-expo * 9.210340371976184f);
  float ang = (float)ids[t * 3 + axis] * freq;
  float s, c; sincosf(ang, &s, &c);
  const void* qw = txt ? naqw : nqw;
  const void* kw = txt ? nakw : nkw;
  float w0q = loadf(qw, 2 * lane, f32), w1q = loadf(qw, 2 * lane + 1, f32);
  float w0k = loadf(kw, 2 * lane, f32), w1k = loadf(kw, 2 * lane + 1, f32);
  const float QS = 0.08838834764831845f * 1.4426950408889634f;
#pragma unroll
  for (int i = 0; i < 3; ++i) {
    int h = wv + 8 * i;
    short* qp = qkv + (size_t)t * 9216 + h * 128 + 2 * lane;
    short* kp = qp + 3072;
    union { unsigned u; short sh[2]; } qv, kv;
    qv.u = *(const unsigned*)qp;
    kv.u = *(const unsigned*)kp;
    float q0 = b2f(qv.sh[0]), q1 = b2f(qv.sh[1]);
    float k0 = b2f(kv.sh[0]), k1 = b2f(kv.sh[1]);
    float sq = q0 * q0 + q1 * q1, sk = k0 * k0 + k1 * k1;
#pragma unroll
    for (int o = 1; o < 64; o <<= 1) { sq += __shfl_xor(sq, o); sk += __shfl_xor(sk, o); }
    float rq = rsqrtf(sq * (1.0f / 128.0f) + 1e-5f);
    float rk = rsqrtf(sk * (1.0f / 128.0f) + 1e-5f);
    float qn0 = q0 * rq * w0q, qn1 = q1 * rq * w1q;
    float kn0 = k0 * rk * w0k, kn1 = k1 * rk * w1k;
    float qo0 = qn0 * c - qn1 * s, qo1 = qn1 * c + qn0 * s;
    float ko0 = kn0 * c - kn1 * s, ko1 = kn1 * c + kn0 * s;
    union { unsigned u; short sh[2]; } qo, ko;
    qo.sh[0] = f2b(qo0 * QS);
    qo.sh[1] = f2b(qo1 * QS);
    ko.sh[0] = f2b(ko0); ko.sh[1] = f2b(ko1);
    *(unsigned*)qp = qo.u;
    *(unsigned*)kp = ko.u;
  }
}

// ---------- flash attention v9 (unchanged).
__global__ __launch_bounds__(512, 2)
void attn_fa(const short* __restrict__ qkv, short* __restrict__ attn) {
  __shared__ short QPs[256 * 128];      // 64 KB
  __shared__ short KVs[2][128 * 128];   // 2 x 32 KB
  const int wgid = blockIdx.x;
  const int xcd = wgid & 7, slot = wgid >> 3;   // 30 slots/XCD
  const int h = xcd * 3 + slot / 10;            // 3 heads per XCD (L2-resident K/V)
  const int qt = slot % 10;
  const int tid = threadIdx.x, lane = tid & 63, w = tid >> 6;  // 8 waves
  const int qg = lane >> 4, l16 = lane & 15;
  const int lr = lane >> 4, lc = lane & 15;
  const int q0 = qt << 8;
  const int sc = tid & 15;
  const int srow5 = (tid >> 4) & 15, half = tid >> 8;

  const short* Qg  = qkv + (size_t)q0 * 9216 + h * 128;
  const short* Kg0 = qkv + 3072 + h * 128;
  const short* Vg0 = qkv + 6144 + h * 128;

  short8 vr[4];
#pragma unroll
  for (int j = 0; j < 8; ++j) {
    int row = j * 32 + w * 4 + lr;
    gload16(Qg + (size_t)row * 9216 + ((lc ^ (row & 7)) << 3),
            QPs + (j * 32 + w * 4) * 128);
  }
#pragma unroll
  for (int j = 0; j < 4; ++j) {
    int row = j * 32 + w * 4 + lr;
    gload16(Kg0 + (size_t)row * 9216 + ((lc ^ (row & 7)) << 3),
            &KVs[0][(j * 32 + w * 4) * 128]);
  }
#pragma unroll
  for (int j = 0; j < 4; ++j) {
    int row = half * 64 + j * 16 + srow5;
    vr[j] = *(const short8*)(Vg0 + (size_t)row * 9216 + sc * 8);
  }
  asm volatile("s_waitcnt vmcnt(8) lgkmcnt(0)" ::: "memory");
  __builtin_amdgcn_s_barrier();
  short8 aq[2][4];
#pragma unroll
  for (int mi = 0; mi < 2; ++mi)
#pragma unroll
    for (int kc = 0; kc < 4; ++kc) {
      int row = w * 32 + mi * 16 + l16;
      aq[mi][kc] = *(const short8*)(QPs + row * 128 + (((kc * 4 + qg) ^ (row & 7)) << 3));
    }

  floatx4 acc_o[2][8];
#pragma unroll
  for (int mi = 0; mi < 2; ++mi)
#pragma unroll
    for (int nd = 0; nd < 8; ++nd) acc_o[mi][nd] = (floatx4){0.f, 0.f, 0.f, 0.f};
  float m_i[2][4], l_i[2][4];
#pragma unroll
  for (int mi = 0; mi < 2; ++mi)
#pragma unroll
    for (int r = 0; r < 4; ++r) { m_i[mi][r] = -1e30f; l_i[mi][r] = 0.0f; }

  for (int kt = 0; kt < 20; ++kt) {
    const int c = kt & 1;
    asm volatile("s_waitcnt vmcnt(4) lgkmcnt(0)" ::: "memory");
    __builtin_amdgcn_s_barrier();
    if (kt < 19) {
      const short* Kg = qkv + ((size_t)(kt + 1) * 128) * 9216 + 3072 + h * 128;
#pragma unroll
      for (int j = 0; j < 4; ++j) {
        int row = j * 32 + w * 4 + lr;
        gload16(Kg + (size_t)row * 9216 + ((lc ^ (row & 7)) << 3),
                &KVs[1 - c][(j * 32 + w * 4) * 128]);
      }
    }
    floatx4 acc_s[2][8];
#pragma unroll
    for (int mi = 0; mi < 2; ++mi)
#pragma unroll
      for (int ni = 0; ni < 8; ++ni) acc_s[mi][ni] = (floatx4){0.f, 0.f, 0.f, 0.f};
    __builtin_amdgcn_s_setprio(1);
#pragma unroll
    for (int kc = 0; kc < 4; ++kc) {
#pragma unroll
      for (int ni = 0; ni < 8; ++ni) {
        int row = ni * 16 + l16;
        short8 b = *(const short8*)(&KVs[c][row * 128 + (((kc * 4 + qg) ^ (row & 7)) << 3)]);
        acc_s[0][ni] = __builtin_amdgcn_mfma_f32_16x16x32_bf16(aq[0][kc], b, acc_s[0][ni], 0, 0, 0);
        acc_s[1][ni] = __builtin_amdgcn_mfma_f32_16x16x32_bf16(aq[1][kc], b, acc_s[1][ni], 0, 0, 0);
      }
    }
    __builtin_amdgcn_s_setprio(0);
    float mxv[2][4];
    bool need = false;
#pragma unroll
    for (int mi = 0; mi < 2; ++mi) {
#pragma unroll
      for (int r = 0; r < 4; ++r) {
        float mx = acc_s[mi][0][r];
#pragma unroll
        for (int ni = 1; ni < 8; ++ni) mx = fmaxf(mx, acc_s[mi][ni][r]);
        mx = fmaxf(mx, __shfl_xor(mx, 1));
        mx = fmaxf(mx, __shfl_xor(mx, 2));
        mx = fmaxf(mx, __shfl_xor(mx, 4));
        mx = fmaxf(mx, __shfl_xor(mx, 8));
        mxv[mi][r] = mx;
        need = need || (mx > m_i[mi][r] + 8.0f);
      }
    }
    if (__ballot(need)) {
#pragma unroll
      for (int mi = 0; mi < 2; ++mi) {
#pragma unroll
        for (int r = 0; r < 4; ++r) {
          float mn = fmaxf(m_i[mi][r], mxv[mi][r]);
          float al = __builtin_amdgcn_exp2f(m_i[mi][r] - mn);
          m_i[mi][r] = mn;
          l_i[mi][r] *= al;
#pragma unroll
          for (int nd = 0; nd < 8; ++nd) acc_o[mi][nd][r] *= al;
        }
      }
    }
#pragma unroll
    for (int mi = 0; mi < 2; ++mi) {
      float rs[4] = {0.f, 0.f, 0.f, 0.f};
#pragma unroll
      for (int r = 0; r < 4; ++r) {
        float pv[8];
#pragma unroll
        for (int ni = 0; ni < 8; ++ni) {
          pv[ni] = __builtin_amdgcn_exp2f(acc_s[mi][ni][r] - m_i[mi][r]);
          rs[r] += pv[ni];
        }
        unsigned u0 = cvtpk(pv[0], pv[1]);
        unsigned u1 = cvtpk(pv[2], pv[3]);
        unsigned u2 = cvtpk(pv[4], pv[5]);
        unsigned u3 = cvtpk(pv[6], pv[7]);
        int row = w * 32 + mi * 16 + qg * 4 + r;
        uint4 uu; uu.x = u0; uu.y = u1; uu.z = u2; uu.w = u3;
        *(uint4*)(QPs + row * 128 + ((l16 ^ (row & 15)) << 3)) = uu;
      }
#pragma unroll
      for (int r = 0; r < 4; ++r) {
        float t = rs[r];
        t += __shfl_xor(t, 1); t += __shfl_xor(t, 2);
        t += __shfl_xor(t, 4); t += __shfl_xor(t, 8);
        l_i[mi][r] += t;
      }
    }
    asm volatile("s_waitcnt lgkmcnt(0)" ::: "memory");
    __builtin_amdgcn_s_barrier();
#pragma unroll
    for (int u = 0; u < 8; ++u) {
      int d = sc * 8 + u;
      short4v pk = { vr[0][u], vr[1][u], vr[2][u], vr[3][u] };
      *(short4v*)(&KVs[c][d * 128 + (((srow5 ^ u ^ (sc & 7))) << 3) + half * 4]) = pk;
    }
    if (kt < 19) {
      const short* Vg = qkv + ((size_t)(kt + 1) * 128) * 9216 + 6144 + h * 128;
#pragma unroll
      for (int j = 0; j < 4; ++j) {
        int row = half * 64 + j * 16 + srow5;
        vr[j] = *(const short8*)(Vg + (size_t)row * 9216 + sc * 8);
      }
    }
    asm volatile("s_waitcnt lgkmcnt(0)" ::: "memory");
    __builtin_amdgcn_s_barrier();
    __builtin_amdgcn_s_setprio(1);
#pragma unroll
    for (int kc = 0; kc < 4; ++kc) {
      int prow0 = w * 32 + l16;
      short8 ap0 = *(const short8*)(QPs + prow0 * 128 + (((kc * 4 + qg) ^ (prow0 & 15)) << 3));
      int prow1 = prow0 + 16;
      short8 ap1 = *(const short8*)(QPs + prow1 * 128 + (((kc * 4 + qg) ^ (prow1 & 15)) << 3));
#pragma unroll
      for (int nd = 0; nd < 8; ++nd) {
        int row = nd * 16 + l16;
        int chn = (kc * 4 + qg) ^ (row & 7) ^ ((row >> 3) & 7);
        short8 b = *(const short8*)(&KVs[c][row * 128 + (chn << 3)]);
        acc_o[0][nd] = __builtin_amdgcn_mfma_f32_16x16x32_bf16(ap0, b, acc_o[0][nd], 0, 0, 0);
        acc_o[1][nd] = __builtin_amdgcn_mfma_f32_16x16x32_bf16(ap1, b, acc_o[1][nd], 0, 0, 0);
      }
    }
    __builtin_amdgcn_s_setprio(0);
  }
#pragma unroll
  for (int mi = 0; mi < 2; ++mi) {
    float inv[4];
#pragma unroll
    for (int r = 0; r < 4; ++r) inv[r] = 1.0f / l_i[mi][r];
#pragma unroll
    for (int nd = 0; nd < 8; ++nd) {
#pragma unroll
      for (int r = 0; r < 4; ++r) {
        int row = w * 32 + mi * 16 + qg * 4 + r;
        QPs[row * 128 + nd * 16 + l16] = f2b(acc_o[mi][nd][r] * inv[r]);
      }
    }
  }
  asm volatile("s_waitcnt lgkmcnt(0)" ::: "memory");
#pragma unroll
  for (int j = 0; j < 8; ++j) {
    int rrow = w * 32 + j * 4 + qg;
    short8 vv = *(const short8*)(QPs + rrow * 128 + l16 * 8);
    *(short8*)(attn + (size_t)(q0 + rrow) * 3072 + h * 128 + l16 * 8) = vv;
  }
}

extern "C" void kernel_launch(void* const* d_in, const int* in_sizes, int n_in,
                              void* d_out, int out_size, void* d_ws, size_t ws_size,
                              hipStream_t stream) {
  (void)in_sizes; (void)n_in; (void)out_size;
  const void* hidden    = d_in[0];
  const void* enc       = d_in[1];
  const int*  ids       = (const int*)d_in[2];
  const void* w_qkv     = d_in[3];
  const void* w_add_qkv = d_in[4];
  const void* b_add_qkv = d_in[5];
  const void* w_out     = d_in[6];
  const void* b_out     = d_in[7];
  const void* w_add_out = d_in[8];
  const void* b_add_out = d_in[9];
  const void* nqw  = d_in[10];
  const void* nkw  = d_in[11];
  const void* naqw = d_in[12];
  const void* nakw = d_in[13];

  int*   dflag = (int*)d_ws;
  short* qkv   = (short*)((char*)d_ws + 256);   // [2560][9216] bf16
  short* attnB = qkv + (size_t)2560 * 9216;     // [2560][3072] bf16

  short* pool  = attnB + (size_t)2560 * 3072;
  const long n_hid  = 2048L * 3072;
  const long n_enc  = 512L * 3072;
  const long n_wqkv = 3072L * 9216;
  const long n_wout = 3072L * 3072;
  short* xb   = pool;                    // [2560][3072]
  short* wqb  = xb + n_enc + n_hid;      // w_qkv^T    [9216][3072]
  short* waqb = wqb + n_wqkv;            // w_add_qkv^T[9216][3072]
  short* wob  = waqb + n_wqkv;           // w_out^T    [3072][3072]
  short* waob = wob + n_wout;            // w_add_out^T[3072][3072]
  const size_t REQ = 256 + 2 * ((size_t)2560 * 9216 + (size_t)2560 * 3072 +
                                n_hid + n_enc + 2 * n_wqkv + 2 * n_wout);

  detect_dtype<<<1, 256, 0, stream>>>((const unsigned short*)w_qkv, dflag);

  if (ws_size >= REQ) {
    cvt_bf16_2<<<1024, 256, 0, stream>>>(enc, n_enc / 8, hidden, n_hid / 8, xb, dflag);
    cvt_tw<<<dim3(18432), 256, 0, stream>>>(w_qkv, wqb, w_add_qkv, waqb,
                                            w_out, wob, w_add_out, waob, dflag);

    // merged QKV projection, 256-row tiles: y<2 -> enc (bias), y>=2 -> hidden
    gemm_bf2<<<dim3(72, 10), 256, 0, stream>>>(
        xb, waqb, b_add_qkv, 0, 0, 2, wqb, nullptr, 512, 512,
        qkv, 9216, 3072, dflag, 0);
    norm_rope<<<dim3(2560), 512, 0, stream>>>(qkv, ids, nqw, nkw, naqw, nakw, dflag);
    attn_fa<<<dim3(240), 512, 0, stream>>>(qkv, attnB);
    // merged out-proj, 256-row tiles: y<8 -> img; y>=8 -> enc
    gemm_bf2<<<dim3(24, 10), 256, 0, stream>>>(
        attnB, wob, b_out, 512, 0, 8, waob, b_add_out, 0, 2048,
        d_out, 3072, 3072, dflag, 1);
  } else {
    gemm_bt<<<dim3(72, 4), 256, 0, stream>>>(enc, 0, w_add_qkv, b_add_qkv, qkv, 0, 9216, 3072, dflag, 1, 0);
    gemm_bt<<<dim3(72, 16), 256, 0, stream>>>(hidden, 0, w_qkv, nullptr, qkv, 512, 9216, 3072, dflag, 1, 0);
    norm_rope<<<dim3(2560), 512, 0, stream>>>(qkv, ids, nqw, nkw, naqw, nakw, dflag);
    attn_fa<<<dim3(240), 512, 0, stream>>>(qkv, attnB);
    gemm_bt<<<dim3(24, 16), 256, 0, stream>>>(attnB, 512, w_out, b_out, d_out, 0, 3072, 3072, dflag, 0, 1);
    gemm_bt<<<dim3(24, 4), 256, 0, stream>>>(attnB, 0, w_add_out, b_add_out, d_out, 2048, 3072, 3072, dflag, 0, 1);
  }
}

// Round 17
// 792.835 us; speedup vs baseline: 1.0001x; 1.0001x over previous
//
#include <hip/hip_runtime.h>

typedef __attribute__((ext_vector_type(8))) short short8;
typedef __attribute__((ext_vector_type(4))) short short4v;
typedef __attribute__((ext_vector_type(4))) float floatx4;

__device__ __forceinline__ float b2f(short b) {
  union { unsigned u; float f; } v; v.u = ((unsigned)(unsigned short)b) << 16; return v.f;
}
__device__ __forceinline__ short f2b(float f) {
  union { float f; unsigned u; } v; v.f = f;
  return (short)((v.u + 0x7fffu + ((v.u >> 16) & 1u)) >> 16);
}
// packed f32x2 -> bf16x2 (RNE), single VOP3 instr
__device__ __forceinline__ unsigned cvtpk(float lo, float hi) {
  unsigned r;
  asm("v_cvt_pk_bf16_f32 %0, %1, %2" : "=v"(r) : "v"(lo), "v"(hi));
  return r;
}
__device__ __forceinline__ float loadf(const void* p, size_t i, bool f32) {
  return f32 ? ((const float*)p)[i] : b2f(((const short*)p)[i]);
}
__device__ __forceinline__ short8 load8(const void* p, size_t i, bool f32) {
  if (f32) {
    const float* fp = (const float*)p + i;
    float4 a = *(const float4*)fp;
    float4 b = *(const float4*)(fp + 4);
    short8 r;
    r[0] = f2b(a.x); r[1] = f2b(a.y); r[2] = f2b(a.z); r[3] = f2b(a.w);
    r[4] = f2b(b.x); r[5] = f2b(b.y); r[6] = f2b(b.z); r[7] = f2b(b.w);
    return r;
  }
  return *(const short8*)((const short*)p + i);
}

// async global->LDS, 16B per lane. LDS dest = wave-uniform base + lane*16.
__device__ __forceinline__ void gload16(const short* g, short* l) {
  __builtin_amdgcn_global_load_lds(
      (const __attribute__((address_space(1))) unsigned int*)g,
      (__attribute__((address_space(3))) unsigned int*)l, 16, 0, 0);
}

// ---------- dtype detector
__global__ void detect_dtype(const unsigned short* __restrict__ w, int* __restrict__ flag) {
  __shared__ int cnt;
  if (threadIdx.x == 0) cnt = 0;
  __syncthreads();
  int bad = 0;
  for (int i = threadIdx.x; i < 4096; i += 256) {
    int e = (w[i] >> 7) & 0xFF;
    if (e >= 0xC8) bad++;
  }
  atomicAdd(&cnt, bad);
  __syncthreads();
  if (threadIdx.x == 0) *flag = (cnt > 64) ? 1 : 0;
}

// ---------- one-time dtype normalization: two sources -> one contiguous dst
__global__ __launch_bounds__(256)
void cvt_bf16_2(const void* __restrict__ srcA, long n8A,
                const void* __restrict__ srcB, long n8B,
                short* __restrict__ dst, const int* __restrict__ dflag) {
  const bool f32 = (*dflag != 0);
  const long n8 = n8A + n8B;
  long stride = (long)gridDim.x * 256;
  for (long i = (long)blockIdx.x * 256 + threadIdx.x; i < n8; i += stride) {
    const void* s; long e;
    if (i < n8A) { s = srcA; e = i * 8; } else { s = srcB; e = (i - n8A) * 8; }
    if (f32) {
      const float* fp = (const float*)s + e;
      float4 a = *(const float4*)fp;
      float4 b = *(const float4*)(fp + 4);
      short8 r;
      r[0] = f2b(a.x); r[1] = f2b(a.y); r[2] = f2b(a.z); r[3] = f2b(a.w);
      r[4] = f2b(b.x); r[5] = f2b(b.y); r[6] = f2b(b.z); r[7] = f2b(b.w);
      *(short8*)(dst + i * 8) = r;
    } else {
      *(short8*)(dst + i * 8) = *(const short8*)((const short*)s + e);
    }
  }
}

// ---------- cvt_tw: all 4 weight transposes in ONE launch (1-D grid decode).
__global__ __launch_bounds__(256)
void cvt_tw(const void* __restrict__ wq, short* __restrict__ wqd,
            const void* __restrict__ waq, short* __restrict__ waqd,
            const void* __restrict__ wo, short* __restrict__ wod,
            const void* __restrict__ wao, short* __restrict__ waod,
            const int* __restrict__ dflag) {
  __shared__ short st[64][72];
  const bool f32 = (*dflag != 0);
  const int K = 3072;
  int b = blockIdx.x;
  const void* src; short* dst; int N, n0, k0;
  if (b < 13824) {               // two big matrices: 2 x (144 x 48)
    src = (b < 6912) ? wq : waq;
    dst = (b < 6912) ? wqd : waqd;
    int rem = b % 6912;
    N = 9216; n0 = (rem % 144) << 6; k0 = (rem / 144) << 6;
  } else {                       // two small: 2 x (48 x 48)
    b -= 13824;
    src = (b < 2304) ? wo : wao;
    dst = (b < 2304) ? wod : waod;
    int rem = b % 2304;
    N = 3072; n0 = (rem % 48) << 6; k0 = (rem / 48) << 6;
  }
  const int c4 = threadIdx.x & 15;
  const int rq = threadIdx.x >> 4;
#pragma unroll
  for (int r = 0; r < 4; ++r) {
    int k = r * 16 + rq;
    int n = c4 * 4;
    short v0, v1, v2, v3;
    if (f32) {
      const float* sp = (const float*)src + (size_t)(k0 + k) * N + n0 + n;
      float4 f = *(const float4*)sp;
      v0 = f2b(f.x); v1 = f2b(f.y); v2 = f2b(f.z); v3 = f2b(f.w);
    } else {
      const short* sp = (const short*)src + (size_t)(k0 + k) * N + n0 + n;
      short4v s = *(const short4v*)sp;
      v0 = s[0]; v1 = s[1]; v2 = s[2]; v3 = s[3];
    }
    st[n + 0][k] = v0; st[n + 1][k] = v1; st[n + 2][k] = v2; st[n + 3][k] = v3;
  }
  __syncthreads();
  const int n = threadIdx.x >> 2;
  const int kc = (threadIdx.x & 3) << 4;
  short8 a = *(const short8*)(&st[n][kc]);
  short8 bb = *(const short8*)(&st[n][kc + 8]);
  short* dp = dst + (size_t)(n0 + n) * K + k0 + kc;
  *(short8*)(dp) = a;
  *(short8*)(dp + 8) = bb;
}

// ---------- OLD GEMM (fallback) ----------
__global__ __launch_bounds__(256, 2)
void gemm_bt(const void* __restrict__ A, int a_row0,
             const void* __restrict__ B, const void* __restrict__ bias,
             void* __restrict__ C, int c_row0, int N, int K,
             const int* __restrict__ dflag, int aIn, int cOut) {
  __shared__ short As[128 * 32];
  __shared__ short Bs[128 * 32];
  const bool f32 = (*dflag != 0);
  const bool a32 = aIn && f32;
  const bool c32 = cOut && f32;
  const int tid = threadIdx.x;
  const int lane = tid & 63, w = tid >> 6;
  const int wm = w & 1, wn = w >> 1;
  const int qg = lane >> 4, l16 = lane & 15;
  const int m0 = blockIdx.y << 7, n0 = blockIdx.x << 7;

  const int arow = tid >> 2, ak = (tid & 3) << 3;
  const int brow = tid >> 4, bc = (tid & 15) << 3;
  const int rot = tid & 15;

  floatx4 acc[4][4];
#pragma unroll
  for (int i = 0; i < 4; ++i)
#pragma unroll
    for (int j = 0; j < 4; ++j) acc[i][j] = (floatx4){0.f, 0.f, 0.f, 0.f};

  for (int k0 = 0; k0 < K; k0 += 32) {
    __syncthreads();
#pragma unroll
    for (int j = 0; j < 2; ++j) {
      short8 av = load8(A, (size_t)(a_row0 + m0 + j * 64 + arow) * K + (k0 + ak), a32);
      *(short8*)(As + (j * 64 + arow) * 32 + ak) = av;
      int kr = j * 16 + brow;
      short8 bv = load8(B, (size_t)(k0 + kr) * N + (n0 + bc), f32);
      int kq = kr >> 3, kj = kr & 7;
#pragma unroll
      for (int s = 0; s < 8; ++s) {
        int u = (s + rot) & 7;
        int n = bc + u;
        Bs[(n << 5) + ((kq ^ (n & 3)) << 3) + kj] = bv[u];
      }
    }
    __syncthreads();
    short8 a[4];
#pragma unroll
    for (int mi = 0; mi < 4; ++mi)
      a[mi] = *(const short8*)(As + (wm * 64 + mi * 16 + l16) * 32 + qg * 8);
#pragma unroll
    for (int ni = 0; ni < 4; ++ni) {
      int n = wn * 64 + ni * 16 + l16;
      short8 b = *(const short8*)(Bs + (n << 5) + ((qg ^ (n & 3)) << 3));
#pragma unroll
      for (int mi = 0; mi < 4; ++mi)
        acc[mi][ni] = __builtin_amdgcn_mfma_f32_16x16x32_bf16(a[mi], b, acc[mi][ni], 0, 0, 0);
    }
  }
#pragma unroll
  for (int ni = 0; ni < 4; ++ni) {
    int col = n0 + wn * 64 + ni * 16 + l16;
    float bv = bias ? loadf(bias, col, f32) : 0.0f;
#pragma unroll
    for (int mi = 0; mi < 4; ++mi) {
      int row = m0 + wm * 64 + mi * 16 + qg * 4;
#pragma unroll
      for (int r = 0; r < 4; ++r) {
        size_t idx = (size_t)(c_row0 + row + r) * N + col;
        float val = acc[mi][ni][r] + bv;
        if (c32) ((float*)C)[idx] = val;
        else     ((short*)C)[idx] = f2b(val);
      }
    }
  }
}

// ---------- GEMM v11 (qkv): 256x128 block tile, 128x64 wave tile, depth-2
// pipeline, single barrier/K-step, counted vmcnt(6), coalesced epilogue.
// Used where the grid is large (qkv: 720 blocks on 512 2/CU slots).
__global__ __launch_bounds__(256, 2)
void gemm_bf2(const short* __restrict__ A,
              const short* __restrict__ BTa, const void* __restrict__ biasa,
              int a0a, int c0a, int nYa,
              const short* __restrict__ BTb, const void* __restrict__ biasb,
              int a0b, int c0b,
              void* __restrict__ C, int N, int K,
              const int* __restrict__ dflag, int cOut) {
  __shared__ short Ls[3 * 8192 + 3 * 4096];    // 72 KB
#define ASB(b) (Ls + (b) * 8192)
#define BSB(b) (Ls + 24576 + (b) * 4096)
  const bool f32 = (*dflag != 0);
  const bool c32 = cOut && f32;
  const int bx = blockIdx.x;
  const int y = blockIdx.y;
  const short* BT; const void* bias; int arow0, crow0;
  if (y < nYa) { BT = BTa; bias = biasa; arow0 = a0a + (y << 8); crow0 = c0a + (y << 8); }
  else { int my = y - nYa; BT = BTb; bias = biasb; arow0 = a0b + (my << 8); crow0 = c0b + (my << 8); }
  const int tid = threadIdx.x;
  const int lane = tid & 63, w = tid >> 6;
  const int wm = w & 1, wn = w >> 1;
  const int qg = lane >> 4, l16 = lane & 15;
  const int n0 = bx << 7;
  const int garow = lane >> 2;
  const int gcir = lane & 3;
  const int nk = K >> 5;
  const int swz = (gcir ^ (garow & 3) ^ (garow >> 2)) << 3;
  const short* Abase = A + (size_t)(arow0 + w * 64 + garow) * K + swz;
  const short* Bbase = BT + (size_t)(n0 + w * 32 + garow) * K + swz;
  const int rswz = (l16 & 3) ^ (l16 >> 2);

  floatx4 acc[8][4];
#pragma unroll
  for (int i = 0; i < 8; ++i)
#pragma unroll
    for (int j = 0; j < 4; ++j) acc[i][j] = (floatx4){0.f, 0.f, 0.f, 0.f};

  auto STAGE = [&](int buf, int k0) {
#pragma unroll
    for (int j = 0; j < 4; ++j)
      gload16(Abase + (size_t)j * 16 * K + k0, ASB(buf) + ((w * 4 + j) << 9));
#pragma unroll
    for (int j = 0; j < 2; ++j)
      gload16(Bbase + (size_t)j * 16 * K + k0, BSB(buf) + ((w * 2 + j) << 9));
  };

  STAGE(0, 0);
  if (nk > 1) STAGE(1, 32);

  int cb = 0;
  for (int t = 0; t < nk; ++t) {
    if (t + 1 < nk) {
      asm volatile("s_waitcnt vmcnt(6) lgkmcnt(0)" ::: "memory");
    } else {
      asm volatile("s_waitcnt vmcnt(0) lgkmcnt(0)" ::: "memory");
    }
    __builtin_amdgcn_s_barrier();
    if (t + 2 < nk) {
      int sb = (cb == 0) ? 2 : cb - 1;
      STAGE(sb, (t + 2) << 5);
    }
    short8 a[8], b[4];
#pragma unroll
    for (int mi = 0; mi < 8; ++mi) {
      int ra = wm * 128 + mi * 16 + l16;
      a[mi] = *(const short8*)(ASB(cb) + (ra << 5) + ((qg ^ rswz) << 3));
    }
#pragma unroll
    for (int ni = 0; ni < 4; ++ni) {
      int n = wn * 64 + ni * 16 + l16;
      b[ni] = *(const short8*)(BSB(cb) + (n << 5) + ((qg ^ rswz) << 3));
    }
    __builtin_amdgcn_s_setprio(1);
#pragma unroll
    for (int ni = 0; ni < 4; ++ni)
#pragma unroll
      for (int mi = 0; mi < 8; ++mi)
        acc[mi][ni] = __builtin_amdgcn_mfma_f32_16x16x32_bf16(a[mi], b[ni], acc[mi][ni], 0, 0, 0);
    __builtin_amdgcn_s_setprio(0);
    cb = (cb == 2) ? 0 : cb + 1;
  }
  __builtin_amdgcn_s_barrier();
  if (!c32) {
    short* wreg = Ls + w * 4096;
#pragma unroll
    for (int half = 0; half < 2; ++half) {
#pragma unroll
      for (int ni = 0; ni < 4; ++ni) {
        float bvv = bias ? loadf(bias, n0 + wn * 64 + ni * 16 + l16, f32) : 0.0f;
#pragma unroll
        for (int mi2 = 0; mi2 < 4; ++mi2)
#pragma unroll
          for (int r = 0; r < 4; ++r)
            wreg[(mi2 * 16 + qg * 4 + r) * 64 + ni * 16 + l16] =
                f2b(acc[half * 4 + mi2][ni][r] + bvv);
      }
      asm volatile("s_waitcnt lgkmcnt(0)" ::: "memory");
#pragma unroll
      for (int j = 0; j < 8; ++j) {
        int row = j * 8 + (lane >> 3);
        int col = (lane & 7) * 8;
        short8 v = *(const short8*)(wreg + row * 64 + col);
        *(short8*)((short*)C + (size_t)(crow0 + wm * 128 + half * 64 + row) * N +
                   n0 + wn * 64 + col) = v;
      }
      asm volatile("s_waitcnt lgkmcnt(0)" ::: "memory");
    }
  } else {
    float* wregf = (float*)(Ls) + w * 2048;
#pragma unroll
    for (int half = 0; half < 2; ++half) {
#pragma unroll
      for (int ch = 0; ch < 2; ++ch) {
#pragma unroll
        for (int nh = 0; nh < 2; ++nh) {
          int ni = ch * 2 + nh;
          float bvv = bias ? loadf(bias, n0 + wn * 64 + ni * 16 + l16, f32) : 0.0f;
#pragma unroll
          for (int mi2 = 0; mi2 < 4; ++mi2)
#pragma unroll
            for (int r = 0; r < 4; ++r)
              wregf[(mi2 * 16 + qg * 4 + r) * 32 + nh * 16 + l16] =
                  acc[half * 4 + mi2][ni][r] + bvv;
        }
        asm volatile("s_waitcnt lgkmcnt(0)" ::: "memory");
#pragma unroll
        for (int j = 0; j < 8; ++j) {
          int row = j * 8 + (lane >> 3);
          int c4 = (lane & 7) * 4;
          float4 v = *(const float4*)(wregf + row * 32 + c4);
          *(float4*)((float*)C + (size_t)(crow0 + wm * 128 + half * 64 + row) * N +
                     n0 + wn * 64 + ch * 32 + c4) = v;
        }
        asm volatile("s_waitcnt lgkmcnt(0)" ::: "memory");
      }
    }
  }
#undef ASB
#undef BSB
}

// ---------- GEMM v10 variant (out-proj): 128x128 block tile, 64x64 wave tile,
// 3 blocks/CU. R16 regression fix: v11's 256-row tile shrank the out-proj grid
// to 240 blocks on 512 slots (half the CUs idle); this 128-row variant gives
// 480 blocks on 768 slots. Same pipeline skeleton + coalesced epilogue.
__global__ __launch_bounds__(256, 3)
void gemm_bf128(const short* __restrict__ A,
                const short* __restrict__ BTa, const void* __restrict__ biasa,
                int a0a, int c0a, int nYa,
                const short* __restrict__ BTb, const void* __restrict__ biasb,
                int a0b, int c0b,
                void* __restrict__ C, int N, int K,
                const int* __restrict__ dflag, int cOut) {
  __shared__ short Ls[6 * 128 * 32];           // 48 KB
#define ASB(b) (Ls + (b) * 4096)
#define BSB(b) (Ls + (3 + (b)) * 4096)
  const bool f32 = (*dflag != 0);
  const bool c32 = cOut && f32;
  const int bx = blockIdx.x;
  const int y = blockIdx.y;
  const short* BT; const void* bias; int arow0, crow0;
  if (y < nYa) { BT = BTa; bias = biasa; arow0 = a0a + (y << 7); crow0 = c0a + (y << 7); }
  else { int my = y - nYa; BT = BTb; bias = biasb; arow0 = a0b + (my << 7); crow0 = c0b + (my << 7); }
  const int tid = threadIdx.x;
  const int lane = tid & 63, w = tid >> 6;
  const int wm = w & 1, wn = w >> 1;
  const int qg = lane >> 4, l16 = lane & 15;
  const int n0 = bx << 7;
  const int garow = lane >> 2;
  const int gcir = lane & 3;
  const int nk = K >> 5;
  const int swz = (gcir ^ (garow & 3) ^ (garow >> 2)) << 3;
  const short* Abase = A + (size_t)(arow0 + w * 32 + garow) * K + swz;
  const short* Bbase = BT + (size_t)(n0 + w * 32 + garow) * K + swz;
  const int rswz = (l16 & 3) ^ (l16 >> 2);

  floatx4 acc[4][4];
#pragma unroll
  for (int i = 0; i < 4; ++i)
#pragma unroll
    for (int j = 0; j < 4; ++j) acc[i][j] = (floatx4){0.f, 0.f, 0.f, 0.f};

  auto STAGE = [&](int buf, int k0) {
#pragma unroll
    for (int j = 0; j < 2; ++j) {
      gload16(Abase + (size_t)j * 16 * K + k0, ASB(buf) + ((w * 2 + j) << 9));
      gload16(Bbase + (size_t)j * 16 * K + k0, BSB(buf) + ((w * 2 + j) << 9));
    }
  };

  STAGE(0, 0);
  if (nk > 1) STAGE(1, 32);

  int cb = 0;
  for (int t = 0; t < nk; ++t) {
    if (t + 1 < nk) {
      asm volatile("s_waitcnt vmcnt(4) lgkmcnt(0)" ::: "memory");
    } else {
      asm volatile("s_waitcnt vmcnt(0) lgkmcnt(0)" ::: "memory");
    }
    __builtin_amdgcn_s_barrier();
    if (t + 2 < nk) {
      int sb = (cb == 0) ? 2 : cb - 1;
      STAGE(sb, (t + 2) << 5);
    }
    short8 a[4], b[4];
#pragma unroll
    for (int mi = 0; mi < 4; ++mi) {
      int ra = wm * 64 + mi * 16 + l16;
      a[mi] = *(const short8*)(ASB(cb) + (ra << 5) + ((qg ^ rswz) << 3));
    }
#pragma unroll
    for (int ni = 0; ni < 4; ++ni) {
      int n = wn * 64 + ni * 16 + l16;
      b[ni] = *(const short8*)(BSB(cb) + (n << 5) + ((qg ^ rswz) << 3));
    }
    __builtin_amdgcn_s_setprio(1);
#pragma unroll
    for (int ni = 0; ni < 4; ++ni)
#pragma unroll
      for (int mi = 0; mi < 4; ++mi)
        acc[mi][ni] = __builtin_amdgcn_mfma_f32_16x16x32_bf16(a[mi], b[ni], acc[mi][ni], 0, 0, 0);
    __builtin_amdgcn_s_setprio(0);
    cb = (cb == 2) ? 0 : cb + 1;
  }
  __builtin_amdgcn_s_barrier();
  if (!c32) {
    short* wreg = Ls + w * 4096;
#pragma unroll
    for (int ni = 0; ni < 4; ++ni) {
      float bvv = bias ? loadf(bias, n0 + wn * 64 + ni * 16 + l16, f32) : 0.0f;
#pragma unroll
      for (int mi = 0; mi < 4; ++mi)
#pragma unroll
        for (int r = 0; r < 4; ++r)
          wreg[(mi * 16 + qg * 4 + r) * 64 + ni * 16 + l16] = f2b(acc[mi][ni][r] + bvv);
    }
    asm volatile("s_waitcnt lgkmcnt(0)" ::: "memory");
#pragma unroll
    for (int j = 0; j < 8; ++j) {
      int row = j * 8 + (lane >> 3);
      int col = (lane & 7) * 8;
      short8 v = *(const short8*)(wreg + row * 64 + col);
      *(short8*)((short*)C + (size_t)(crow0 + wm * 64 + row) * N + n0 + wn * 64 + col) = v;
    }
  } else {
    float* wregf = (float*)(Ls) + w * 2048;
#pragma unroll
    for (int half = 0; half < 2; ++half) {
#pragma unroll
      for (int nh = 0; nh < 2; ++nh) {
        int ni = half * 2 + nh;
        float bvv = bias ? loadf(bias, n0 + wn * 64 + ni * 16 + l16, f32) : 0.0f;
#pragma unroll
        for (int mi = 0; mi < 4; ++mi)
#pragma unroll
          for (int r = 0; r < 4; ++r)
            wregf[(mi * 16 + qg * 4 + r) * 32 + nh * 16 + l16] = acc[mi][ni][r] + bvv;
      }
      asm volatile("s_waitcnt lgkmcnt(0)" ::: "memory");
#pragma unroll
      for (int j = 0; j < 8; ++j) {
        int row = j * 8 + (lane >> 3);
        int c4 = (lane & 7) * 4;
        float4 v = *(const float4*)(wregf + row * 32 + c4);
        *(float4*)((float*)C + (size_t)(crow0 + wm * 64 + row) * N + n0 + wn * 64 + half * 32 + c4) = v;
      }
      asm volatile("s_waitcnt lgkmcnt(0)" ::: "memory");
    }
  }
#undef ASB
#undef BSB
}

// ---------- RMSNorm + RoPE: one wave per head; q scaled by rsqrt(128)*log2(e).
__global__ __launch_bounds__(512)
void norm_rope(short* __restrict__ qkv, const int* __restrict__ ids,
               const void* __restrict__ nqw, const void* __restrict__ nkw,
               const void* __restrict__ naqw, const void* __restrict__ nakw,
               const int* __restrict__ dflag) {
  const bool f32 = (*dflag != 0);
  const int t = blockIdx.x, wv = threadIdx.x >> 6, lane = threadIdx.x & 63;
  const bool txt = t < 512;
  int p = lane, axis; float expo;
  if (p < 8)       { axis = 0; expo = (float)(2 * p) * (1.0f / 16.0f); }
  else if (p < 36) { axis = 1; expo = (float)(2 * (p - 8)) * (1.0f / 56.0f); }
  else             { axis = 2; expo = (float)(2 * (p - 36)) * (1.0f / 56.0f); }
  float freq = __expf(-expo * 9.210340371976184f);
  float ang = (float)ids[t * 3 + axis] * freq;
  float s, c; sincosf(ang, &s, &c);
  const void* qw = txt ? naqw : nqw;
  const void* kw = txt ? nakw : nkw;
  float w0q = loadf(qw, 2 * lane, f32), w1q = loadf(qw, 2 * lane + 1, f32);
  float w0k = loadf(kw, 2 * lane, f32), w1k = loadf(kw, 2 * lane + 1, f32);
  const float QS = 0.08838834764831845f * 1.4426950408889634f;
#pragma unroll
  for (int i = 0; i < 3; ++i) {
    int h = wv + 8 * i;
    short* qp = qkv + (size_t)t * 9216 + h * 128 + 2 * lane;
    short* kp = qp + 3072;
    union { unsigned u; short sh[2]; } qv, kv;
    qv.u = *(const unsigned*)qp;
    kv.u = *(const unsigned*)kp;
    float q0 = b2f(qv.sh[0]), q1 = b2f(qv.sh[1]);
    float k0 = b2f(kv.sh[0]), k1 = b2f(kv.sh[1]);
    float sq = q0 * q0 + q1 * q1, sk = k0 * k0 + k1 * k1;
#pragma unroll
    for (int o = 1; o < 64; o <<= 1) { sq += __shfl_xor(sq, o); sk += __shfl_xor(sk, o); }
    float rq = rsqrtf(sq * (1.0f / 128.0f) + 1e-5f);
    float rk = rsqrtf(sk * (1.0f / 128.0f) + 1e-5f);
    float qn0 = q0 * rq * w0q, qn1 = q1 * rq * w1q;
    float kn0 = k0 * rk * w0k, kn1 = k1 * rk * w1k;
    float qo0 = qn0 * c - qn1 * s, qo1 = qn1 * c + qn0 * s;
    float ko0 = kn0 * c - kn1 * s, ko1 = kn1 * c + kn0 * s;
    union { unsigned u; short sh[2]; } qo, ko;
    qo.sh[0] = f2b(qo0 * QS);
    qo.sh[1] = f2b(qo1 * QS);
    ko.sh[0] = f2b(ko0); ko.sh[1] = f2b(ko1);
    *(unsigned*)qp = qo.u;
    *(unsigned*)kp = ko.u;
  }
}

// ---------- flash attention v9 (unchanged).
__global__ __launch_bounds__(512, 2)
void attn_fa(const short* __restrict__ qkv, short* __restrict__ attn) {
  __shared__ short QPs[256 * 128];      // 64 KB
  __shared__ short KVs[2][128 * 128];   // 2 x 32 KB
  const int wgid = blockIdx.x;
  const int xcd = wgid & 7, slot = wgid >> 3;   // 30 slots/XCD
  const int h = xcd * 3 + slot / 10;            // 3 heads per XCD (L2-resident K/V)
  const int qt = slot % 10;
  const int tid = threadIdx.x, lane = tid & 63, w = tid >> 6;  // 8 waves
  const int qg = lane >> 4, l16 = lane & 15;
  const int lr = lane >> 4, lc = lane & 15;
  const int q0 = qt << 8;
  const int sc = tid & 15;
  const int srow5 = (tid >> 4) & 15, half = tid >> 8;

  const short* Qg  = qkv + (size_t)q0 * 9216 + h * 128;
  const short* Kg0 = qkv + 3072 + h * 128;
  const short* Vg0 = qkv + 6144 + h * 128;

  short8 vr[4];
#pragma unroll
  for (int j = 0; j < 8; ++j) {
    int row = j * 32 + w * 4 + lr;
    gload16(Qg + (size_t)row * 9216 + ((lc ^ (row & 7)) << 3),
            QPs + (j * 32 + w * 4) * 128);
  }
#pragma unroll
  for (int j = 0; j < 4; ++j) {
    int row = j * 32 + w * 4 + lr;
    gload16(Kg0 + (size_t)row * 9216 + ((lc ^ (row & 7)) << 3),
            &KVs[0][(j * 32 + w * 4) * 128]);
  }
#pragma unroll
  for (int j = 0; j < 4; ++j) {
    int row = half * 64 + j * 16 + srow5;
    vr[j] = *(const short8*)(Vg0 + (size_t)row * 9216 + sc * 8);
  }
  asm volatile("s_waitcnt vmcnt(8) lgkmcnt(0)" ::: "memory");
  __builtin_amdgcn_s_barrier();
  short8 aq[2][4];
#pragma unroll
  for (int mi = 0; mi < 2; ++mi)
#pragma unroll
    for (int kc = 0; kc < 4; ++kc) {
      int row = w * 32 + mi * 16 + l16;
      aq[mi][kc] = *(const short8*)(QPs + row * 128 + (((kc * 4 + qg) ^ (row & 7)) << 3));
    }

  floatx4 acc_o[2][8];
#pragma unroll
  for (int mi = 0; mi < 2; ++mi)
#pragma unroll
    for (int nd = 0; nd < 8; ++nd) acc_o[mi][nd] = (floatx4){0.f, 0.f, 0.f, 0.f};
  float m_i[2][4], l_i[2][4];
#pragma unroll
  for (int mi = 0; mi < 2; ++mi)
#pragma unroll
    for (int r = 0; r < 4; ++r) { m_i[mi][r] = -1e30f; l_i[mi][r] = 0.0f; }

  for (int kt = 0; kt < 20; ++kt) {
    const int c = kt & 1;
    asm volatile("s_waitcnt vmcnt(4) lgkmcnt(0)" ::: "memory");
    __builtin_amdgcn_s_barrier();
    if (kt < 19) {
      const short* Kg = qkv + ((size_t)(kt + 1) * 128) * 9216 + 3072 + h * 128;
#pragma unroll
      for (int j = 0; j < 4; ++j) {
        int row = j * 32 + w * 4 + lr;
        gload16(Kg + (size_t)row * 9216 + ((lc ^ (row & 7)) << 3),
                &KVs[1 - c][(j * 32 + w * 4) * 128]);
      }
    }
    floatx4 acc_s[2][8];
#pragma unroll
    for (int mi = 0; mi < 2; ++mi)
#pragma unroll
      for (int ni = 0; ni < 8; ++ni) acc_s[mi][ni] = (floatx4){0.f, 0.f, 0.f, 0.f};
    __builtin_amdgcn_s_setprio(1);
#pragma unroll
    for (int kc = 0; kc < 4; ++kc) {
#pragma unroll
      for (int ni = 0; ni < 8; ++ni) {
        int row = ni * 16 + l16;
        short8 b = *(const short8*)(&KVs[c][row * 128 + (((kc * 4 + qg) ^ (row & 7)) << 3)]);
        acc_s[0][ni] = __builtin_amdgcn_mfma_f32_16x16x32_bf16(aq[0][kc], b, acc_s[0][ni], 0, 0, 0);
        acc_s[1][ni] = __builtin_amdgcn_mfma_f32_16x16x32_bf16(aq[1][kc], b, acc_s[1][ni], 0, 0, 0);
      }
    }
    __builtin_amdgcn_s_setprio(0);
    float mxv[2][4];
    bool need = false;
#pragma unroll
    for (int mi = 0; mi < 2; ++mi) {
#pragma unroll
      for (int r = 0; r < 4; ++r) {
        float mx = acc_s[mi][0][r];
#pragma unroll
        for (int ni = 1; ni < 8; ++ni) mx = fmaxf(mx, acc_s[mi][ni][r]);
        mx = fmaxf(mx, __shfl_xor(mx, 1));
        mx = fmaxf(mx, __shfl_xor(mx, 2));
        mx = fmaxf(mx, __shfl_xor(mx, 4));
        mx = fmaxf(mx, __shfl_xor(mx, 8));
        mxv[mi][r] = mx;
        need = need || (mx > m_i[mi][r] + 8.0f);
      }
    }
    if (__ballot(need)) {
#pragma unroll
      for (int mi = 0; mi < 2; ++mi) {
#pragma unroll
        for (int r = 0; r < 4; ++r) {
          float mn = fmaxf(m_i[mi][r], mxv[mi][r]);
          float al = __builtin_amdgcn_exp2f(m_i[mi][r] - mn);
          m_i[mi][r] = mn;
          l_i[mi][r] *= al;
#pragma unroll
          for (int nd = 0; nd < 8; ++nd) acc_o[mi][nd][r] *= al;
        }
      }
    }
#pragma unroll
    for (int mi = 0; mi < 2; ++mi) {
      float rs[4] = {0.f, 0.f, 0.f, 0.f};
#pragma unroll
      for (int r = 0; r < 4; ++r) {
        float pv[8];
#pragma unroll
        for (int ni = 0; ni < 8; ++ni) {
          pv[ni] = __builtin_amdgcn_exp2f(acc_s[mi][ni][r] - m_i[mi][r]);
          rs[r] += pv[ni];
        }
        unsigned u0 = cvtpk(pv[0], pv[1]);
        unsigned u1 = cvtpk(pv[2], pv[3]);
        unsigned u2 = cvtpk(pv[4], pv[5]);
        unsigned u3 = cvtpk(pv[6], pv[7]);
        int row = w * 32 + mi * 16 + qg * 4 + r;
        uint4 uu; uu.x = u0; uu.y = u1; uu.z = u2; uu.w = u3;
        *(uint4*)(QPs + row * 128 + ((l16 ^ (row & 15)) << 3)) = uu;
      }
#pragma unroll
      for (int r = 0; r < 4; ++r) {
        float t = rs[r];
        t += __shfl_xor(t, 1); t += __shfl_xor(t, 2);
        t += __shfl_xor(t, 4); t += __shfl_xor(t, 8);
        l_i[mi][r] += t;
      }
    }
    asm volatile("s_waitcnt lgkmcnt(0)" ::: "memory");
    __builtin_amdgcn_s_barrier();
#pragma unroll
    for (int u = 0; u < 8; ++u) {
      int d = sc * 8 + u;
      short4v pk = { vr[0][u], vr[1][u], vr[2][u], vr[3][u] };
      *(short4v*)(&KVs[c][d * 128 + (((srow5 ^ u ^ (sc & 7))) << 3) + half * 4]) = pk;
    }
    if (kt < 19) {
      const short* Vg = qkv + ((size_t)(kt + 1) * 128) * 9216 + 6144 + h * 128;
#pragma unroll
      for (int j = 0; j < 4; ++j) {
        int row = half * 64 + j * 16 + srow5;
        vr[j] = *(const short8*)(Vg + (size_t)row * 9216 + sc * 8);
      }
    }
    asm volatile("s_waitcnt lgkmcnt(0)" ::: "memory");
    __builtin_amdgcn_s_barrier();
    __builtin_amdgcn_s_setprio(1);
#pragma unroll
    for (int kc = 0; kc < 4; ++kc) {
      int prow0 = w * 32 + l16;
      short8 ap0 = *(const short8*)(QPs + prow0 * 128 + (((kc * 4 + qg) ^ (prow0 & 15)) << 3));
      int prow1 = prow0 + 16;
      short8 ap1 = *(const short8*)(QPs + prow1 * 128 + (((kc * 4 + qg) ^ (prow1 & 15)) << 3));
#pragma unroll
      for (int nd = 0; nd < 8; ++nd) {
        int row = nd * 16 + l16;
        int chn = (kc * 4 + qg) ^ (row & 7) ^ ((row >> 3) & 7);
        short8 b = *(const short8*)(&KVs[c][row * 128 + (chn << 3)]);
        acc_o[0][nd] = __builtin_amdgcn_mfma_f32_16x16x32_bf16(ap0, b, acc_o[0][nd], 0, 0, 0);
        acc_o[1][nd] = __builtin_amdgcn_mfma_f32_16x16x32_bf16(ap1, b, acc_o[1][nd], 0, 0, 0);
      }
    }
    __builtin_amdgcn_s_setprio(0);
  }
#pragma unroll
  for (int mi = 0; mi < 2; ++mi) {
    float inv[4];
#pragma unroll
    for (int r = 0; r < 4; ++r) inv[r] = 1.0f / l_i[mi][r];
#pragma unroll
    for (int nd = 0; nd < 8; ++nd) {
#pragma unroll
      for (int r = 0; r < 4; ++r) {
        int row = w * 32 + mi * 16 + qg * 4 + r;
        QPs[row * 128 + nd * 16 + l16] = f2b(acc_o[mi][nd][r] * inv[r]);
      }
    }
  }
  asm volatile("s_waitcnt lgkmcnt(0)" ::: "memory");
#pragma unroll
  for (int j = 0; j < 8; ++j) {
    int rrow = w * 32 + j * 4 + qg;
    short8 vv = *(const short8*)(QPs + rrow * 128 + l16 * 8);
    *(short8*)(attn + (size_t)(q0 + rrow) * 3072 + h * 128 + l16 * 8) = vv;
  }
}

extern "C" void kernel_launch(void* const* d_in, const int* in_sizes, int n_in,
                              void* d_out, int out_size, void* d_ws, size_t ws_size,
                              hipStream_t stream) {
  (void)in_sizes; (void)n_in; (void)out_size;
  const void* hidden    = d_in[0];
  const void* enc       = d_in[1];
  const int*  ids       = (const int*)d_in[2];
  const void* w_qkv     = d_in[3];
  const void* w_add_qkv = d_in[4];
  const void* b_add_qkv = d_in[5];
  const void* w_out     = d_in[6];
  const void* b_out     = d_in[7];
  const void* w_add_out = d_in[8];
  const void* b_add_out = d_in[9];
  const void* nqw  = d_in[10];
  const void* nkw  = d_in[11];
  const void* naqw = d_in[12];
  const void* nakw = d_in[13];

  int*   dflag = (int*)d_ws;
  short* qkv   = (short*)((char*)d_ws + 256);   // [2560][9216] bf16
  short* attnB = qkv + (size_t)2560 * 9216;     // [2560][3072] bf16

  short* pool  = attnB + (size_t)2560 * 3072;
  const long n_hid  = 2048L * 3072;
  const long n_enc  = 512L * 3072;
  const long n_wqkv = 3072L * 9216;
  const long n_wout = 3072L * 3072;
  short* xb   = pool;                    // [2560][3072]
  short* wqb  = xb + n_enc + n_hid;      // w_qkv^T    [9216][3072]
  short* waqb = wqb + n_wqkv;            // w_add_qkv^T[9216][3072]
  short* wob  = waqb + n_wqkv;           // w_out^T    [3072][3072]
  short* waob = wob + n_wout;            // w_add_out^T[3072][3072]
  const size_t REQ = 256 + 2 * ((size_t)2560 * 9216 + (size_t)2560 * 3072 +
                                n_hid + n_enc + 2 * n_wqkv + 2 * n_wout);

  detect_dtype<<<1, 256, 0, stream>>>((const unsigned short*)w_qkv, dflag);

  if (ws_size >= REQ) {
    cvt_bf16_2<<<1024, 256, 0, stream>>>(enc, n_enc / 8, hidden, n_hid / 8, xb, dflag);
    cvt_tw<<<dim3(18432), 256, 0, stream>>>(w_qkv, wqb, w_add_qkv, waqb,
                                            w_out, wob, w_add_out, waob, dflag);

    // merged QKV projection, 256-row tiles: y<2 -> enc (bias), y>=2 -> hidden
    gemm_bf2<<<dim3(72, 10), 256, 0, stream>>>(
        xb, waqb, b_add_qkv, 0, 0, 2, wqb, nullptr, 512, 512,
        qkv, 9216, 3072, dflag, 0);
    norm_rope<<<dim3(2560), 512, 0, stream>>>(qkv, ids, nqw, nkw, naqw, nakw, dflag);
    attn_fa<<<dim3(240), 512, 0, stream>>>(qkv, attnB);
    // merged out-proj, 128-row tiles (480 blocks, 3 blocks/CU): y<16 img, y>=16 enc
    gemm_bf128<<<dim3(24, 20), 256, 0, stream>>>(
        attnB, wob, b_out, 512, 0, 16, waob, b_add_out, 0, 2048,
        d_out, 3072, 3072, dflag, 1);
  } else {
    gemm_bt<<<dim3(72, 4), 256, 0, stream>>>(enc, 0, w_add_qkv, b_add_qkv, qkv, 0, 9216, 3072, dflag, 1, 0);
    gemm_bt<<<dim3(72, 16), 256, 0, stream>>>(hidden, 0, w_qkv, nullptr, qkv, 512, 9216, 3072, dflag, 1, 0);
    norm_rope<<<dim3(2560), 512, 0, stream>>>(qkv, ids, nqw, nkw, naqw, nakw, dflag);
    attn_fa<<<dim3(240), 512, 0, stream>>>(qkv, attnB);
    gemm_bt<<<dim3(24, 16), 256, 0, stream>>>(attnB, 512, w_out, b_out, d_out, 0, 3072, 3072, dflag, 0, 1);
    gemm_bt<<<dim3(24, 4), 256, 0, stream>>>(attnB, 0, w_add_out, b_add_out, d_out, 2048, 3072, 3072, dflag, 0, 1);
  }
}

// Round 18
// 785.098 us; speedup vs baseline: 1.0100x; 1.0099x over previous
//
#include <hip/hip_runtime.h>

typedef __attribute__((ext_vector_type(8))) short short8;
typedef __attribute__((ext_vector_type(4))) short short4v;
typedef __attribute__((ext_vector_type(4))) float floatx4;

__device__ __forceinline__ float b2f(short b) {
  union { unsigned u; float f; } v; v.u = ((unsigned)(unsigned short)b) << 16; return v.f;
}
__device__ __forceinline__ short f2b(float f) {
  union { float f; unsigned u; } v; v.f = f;
  return (short)((v.u + 0x7fffu + ((v.u >> 16) & 1u)) >> 16);
}
// packed f32x2 -> bf16x2 (RNE), single VOP3 instr
__device__ __forceinline__ unsigned cvtpk(float lo, float hi) {
  unsigned r;
  asm("v_cvt_pk_bf16_f32 %0, %1, %2" : "=v"(r) : "v"(lo), "v"(hi));
  return r;
}
__device__ __forceinline__ float loadf(const void* p, size_t i, bool f32) {
  return f32 ? ((const float*)p)[i] : b2f(((const short*)p)[i]);
}
__device__ __forceinline__ short8 load8(const void* p, size_t i, bool f32) {
  if (f32) {
    const float* fp = (const float*)p + i;
    float4 a = *(const float4*)fp;
    float4 b = *(const float4*)(fp + 4);
    short8 r;
    r[0] = f2b(a.x); r[1] = f2b(a.y); r[2] = f2b(a.z); r[3] = f2b(a.w);
    r[4] = f2b(b.x); r[5] = f2b(b.y); r[6] = f2b(b.z); r[7] = f2b(b.w);
    return r;
  }
  return *(const short8*)((const short*)p + i);
}

// async global->LDS, 16B per lane. LDS dest = wave-uniform base + lane*16.
__device__ __forceinline__ void gload16(const short* g, short* l) {
  __builtin_amdgcn_global_load_lds(
      (const __attribute__((address_space(1))) unsigned int*)g,
      (__attribute__((address_space(3))) unsigned int*)l, 16, 0, 0);
}

// ---------- dtype detector
__global__ void detect_dtype(const unsigned short* __restrict__ w, int* __restrict__ flag) {
  __shared__ int cnt;
  if (threadIdx.x == 0) cnt = 0;
  __syncthreads();
  int bad = 0;
  for (int i = threadIdx.x; i < 4096; i += 256) {
    int e = (w[i] >> 7) & 0xFF;
    if (e >= 0xC8) bad++;
  }
  atomicAdd(&cnt, bad);
  __syncthreads();
  if (threadIdx.x == 0) *flag = (cnt > 64) ? 1 : 0;
}

// ---------- one-time dtype normalization: two sources -> one contiguous dst
__global__ __launch_bounds__(256)
void cvt_bf16_2(const void* __restrict__ srcA, long n8A,
                const void* __restrict__ srcB, long n8B,
                short* __restrict__ dst, const int* __restrict__ dflag) {
  const bool f32 = (*dflag != 0);
  const long n8 = n8A + n8B;
  long stride = (long)gridDim.x * 256;
  for (long i = (long)blockIdx.x * 256 + threadIdx.x; i < n8; i += stride) {
    const void* s; long e;
    if (i < n8A) { s = srcA; e = i * 8; } else { s = srcB; e = (i - n8A) * 8; }
    if (f32) {
      const float* fp = (const float*)s + e;
      float4 a = *(const float4*)fp;
      float4 b = *(const float4*)(fp + 4);
      short8 r;
      r[0] = f2b(a.x); r[1] = f2b(a.y); r[2] = f2b(a.z); r[3] = f2b(a.w);
      r[4] = f2b(b.x); r[5] = f2b(b.y); r[6] = f2b(b.z); r[7] = f2b(b.w);
      *(short8*)(dst + i * 8) = r;
    } else {
      *(short8*)(dst + i * 8) = *(const short8*)((const short*)s + e);
    }
  }
}

// ---------- cvt_tw: all 4 weight transposes in ONE launch (1-D grid decode).
__global__ __launch_bounds__(256)
void cvt_tw(const void* __restrict__ wq, short* __restrict__ wqd,
            const void* __restrict__ waq, short* __restrict__ waqd,
            const void* __restrict__ wo, short* __restrict__ wod,
            const void* __restrict__ wao, short* __restrict__ waod,
            const int* __restrict__ dflag) {
  __shared__ short st[64][72];
  const bool f32 = (*dflag != 0);
  const int K = 3072;
  int b = blockIdx.x;
  const void* src; short* dst; int N, n0, k0;
  if (b < 13824) {
    src = (b < 6912) ? wq : waq;
    dst = (b < 6912) ? wqd : waqd;
    int rem = b % 6912;
    N = 9216; n0 = (rem % 144) << 6; k0 = (rem / 144) << 6;
  } else {
    b -= 13824;
    src = (b < 2304) ? wo : wao;
    dst = (b < 2304) ? wod : waod;
    int rem = b % 2304;
    N = 3072; n0 = (rem % 48) << 6; k0 = (rem / 48) << 6;
  }
  const int c4 = threadIdx.x & 15;
  const int rq = threadIdx.x >> 4;
#pragma unroll
  for (int r = 0; r < 4; ++r) {
    int k = r * 16 + rq;
    int n = c4 * 4;
    short v0, v1, v2, v3;
    if (f32) {
      const float* sp = (const float*)src + (size_t)(k0 + k) * N + n0 + n;
      float4 f = *(const float4*)sp;
      v0 = f2b(f.x); v1 = f2b(f.y); v2 = f2b(f.z); v3 = f2b(f.w);
    } else {
      const short* sp = (const short*)src + (size_t)(k0 + k) * N + n0 + n;
      short4v s = *(const short4v*)sp;
      v0 = s[0]; v1 = s[1]; v2 = s[2]; v3 = s[3];
    }
    st[n + 0][k] = v0; st[n + 1][k] = v1; st[n + 2][k] = v2; st[n + 3][k] = v3;
  }
  __syncthreads();
  const int n = threadIdx.x >> 2;
  const int kc = (threadIdx.x & 3) << 4;
  short8 a = *(const short8*)(&st[n][kc]);
  short8 bb = *(const short8*)(&st[n][kc + 8]);
  short* dp = dst + (size_t)(n0 + n) * K + k0 + kc;
  *(short8*)(dp) = a;
  *(short8*)(dp + 8) = bb;
}

// ---------- OLD GEMM (fallback) ----------
__global__ __launch_bounds__(256, 2)
void gemm_bt(const void* __restrict__ A, int a_row0,
             const void* __restrict__ B, const void* __restrict__ bias,
             void* __restrict__ C, int c_row0, int N, int K,
             const int* __restrict__ dflag, int aIn, int cOut) {
  __shared__ short As[128 * 32];
  __shared__ short Bs[128 * 32];
  const bool f32 = (*dflag != 0);
  const bool a32 = aIn && f32;
  const bool c32 = cOut && f32;
  const int tid = threadIdx.x;
  const int lane = tid & 63, w = tid >> 6;
  const int wm = w & 1, wn = w >> 1;
  const int qg = lane >> 4, l16 = lane & 15;
  const int m0 = blockIdx.y << 7, n0 = blockIdx.x << 7;

  const int arow = tid >> 2, ak = (tid & 3) << 3;
  const int brow = tid >> 4, bc = (tid & 15) << 3;
  const int rot = tid & 15;

  floatx4 acc[4][4];
#pragma unroll
  for (int i = 0; i < 4; ++i)
#pragma unroll
    for (int j = 0; j < 4; ++j) acc[i][j] = (floatx4){0.f, 0.f, 0.f, 0.f};

  for (int k0 = 0; k0 < K; k0 += 32) {
    __syncthreads();
#pragma unroll
    for (int j = 0; j < 2; ++j) {
      short8 av = load8(A, (size_t)(a_row0 + m0 + j * 64 + arow) * K + (k0 + ak), a32);
      *(short8*)(As + (j * 64 + arow) * 32 + ak) = av;
      int kr = j * 16 + brow;
      short8 bv = load8(B, (size_t)(k0 + kr) * N + (n0 + bc), f32);
      int kq = kr >> 3, kj = kr & 7;
#pragma unroll
      for (int s = 0; s < 8; ++s) {
        int u = (s + rot) & 7;
        int n = bc + u;
        Bs[(n << 5) + ((kq ^ (n & 3)) << 3) + kj] = bv[u];
      }
    }
    __syncthreads();
    short8 a[4];
#pragma unroll
    for (int mi = 0; mi < 4; ++mi)
      a[mi] = *(const short8*)(As + (wm * 64 + mi * 16 + l16) * 32 + qg * 8);
#pragma unroll
    for (int ni = 0; ni < 4; ++ni) {
      int n = wn * 64 + ni * 16 + l16;
      short8 b = *(const short8*)(Bs + (n << 5) + ((qg ^ (n & 3)) << 3));
#pragma unroll
      for (int mi = 0; mi < 4; ++mi)
        acc[mi][ni] = __builtin_amdgcn_mfma_f32_16x16x32_bf16(a[mi], b, acc[mi][ni], 0, 0, 0);
    }
  }
#pragma unroll
  for (int ni = 0; ni < 4; ++ni) {
    int col = n0 + wn * 64 + ni * 16 + l16;
    float bv = bias ? loadf(bias, col, f32) : 0.0f;
#pragma unroll
    for (int mi = 0; mi < 4; ++mi) {
      int row = m0 + wm * 64 + mi * 16 + qg * 4;
#pragma unroll
      for (int r = 0; r < 4; ++r) {
        size_t idx = (size_t)(c_row0 + row + r) * N + col;
        float val = acc[mi][ni][r] + bv;
        if (c32) ((float*)C)[idx] = val;
        else     ((short*)C)[idx] = f2b(val);
      }
    }
  }
}

// ---------- GEMM v11 (qkv): 256x128 block tile, 128x64 wave tile, depth-2
// pipeline, single barrier/K-step, counted vmcnt(6), coalesced epilogue.
__global__ __launch_bounds__(256, 2)
void gemm_bf2(const short* __restrict__ A,
              const short* __restrict__ BTa, const void* __restrict__ biasa,
              int a0a, int c0a, int nYa,
              const short* __restrict__ BTb, const void* __restrict__ biasb,
              int a0b, int c0b,
              void* __restrict__ C, int N, int K,
              const int* __restrict__ dflag, int cOut) {
  __shared__ short Ls[3 * 8192 + 3 * 4096];    // 72 KB
#define ASB(b) (Ls + (b) * 8192)
#define BSB(b) (Ls + 24576 + (b) * 4096)
  const bool f32 = (*dflag != 0);
  const bool c32 = cOut && f32;
  const int bx = blockIdx.x;
  const int y = blockIdx.y;
  const short* BT; const void* bias; int arow0, crow0;
  if (y < nYa) { BT = BTa; bias = biasa; arow0 = a0a + (y << 8); crow0 = c0a + (y << 8); }
  else { int my = y - nYa; BT = BTb; bias = biasb; arow0 = a0b + (my << 8); crow0 = c0b + (my << 8); }
  const int tid = threadIdx.x;
  const int lane = tid & 63, w = tid >> 6;
  const int wm = w & 1, wn = w >> 1;
  const int qg = lane >> 4, l16 = lane & 15;
  const int n0 = bx << 7;
  const int garow = lane >> 2;
  const int gcir = lane & 3;
  const int nk = K >> 5;
  const int swz = (gcir ^ (garow & 3) ^ (garow >> 2)) << 3;
  const short* Abase = A + (size_t)(arow0 + w * 64 + garow) * K + swz;
  const short* Bbase = BT + (size_t)(n0 + w * 32 + garow) * K + swz;
  const int rswz = (l16 & 3) ^ (l16 >> 2);

  floatx4 acc[8][4];
#pragma unroll
  for (int i = 0; i < 8; ++i)
#pragma unroll
    for (int j = 0; j < 4; ++j) acc[i][j] = (floatx4){0.f, 0.f, 0.f, 0.f};

  auto STAGE = [&](int buf, int k0) {
#pragma unroll
    for (int j = 0; j < 4; ++j)
      gload16(Abase + (size_t)j * 16 * K + k0, ASB(buf) + ((w * 4 + j) << 9));
#pragma unroll
    for (int j = 0; j < 2; ++j)
      gload16(Bbase + (size_t)j * 16 * K + k0, BSB(buf) + ((w * 2 + j) << 9));
  };

  STAGE(0, 0);
  if (nk > 1) STAGE(1, 32);

  int cb = 0;
  for (int t = 0; t < nk; ++t) {
    if (t + 1 < nk) {
      asm volatile("s_waitcnt vmcnt(6) lgkmcnt(0)" ::: "memory");
    } else {
      asm volatile("s_waitcnt vmcnt(0) lgkmcnt(0)" ::: "memory");
    }
    __builtin_amdgcn_s_barrier();
    if (t + 2 < nk) {
      int sb = (cb == 0) ? 2 : cb - 1;
      STAGE(sb, (t + 2) << 5);
    }
    short8 a[8], b[4];
#pragma unroll
    for (int mi = 0; mi < 8; ++mi) {
      int ra = wm * 128 + mi * 16 + l16;
      a[mi] = *(const short8*)(ASB(cb) + (ra << 5) + ((qg ^ rswz) << 3));
    }
#pragma unroll
    for (int ni = 0; ni < 4; ++ni) {
      int n = wn * 64 + ni * 16 + l16;
      b[ni] = *(const short8*)(BSB(cb) + (n << 5) + ((qg ^ rswz) << 3));
    }
    __builtin_amdgcn_s_setprio(1);
#pragma unroll
    for (int ni = 0; ni < 4; ++ni)
#pragma unroll
      for (int mi = 0; mi < 8; ++mi)
        acc[mi][ni] = __builtin_amdgcn_mfma_f32_16x16x32_bf16(a[mi], b[ni], acc[mi][ni], 0, 0, 0);
    __builtin_amdgcn_s_setprio(0);
    cb = (cb == 2) ? 0 : cb + 1;
  }
  __builtin_amdgcn_s_barrier();
  if (!c32) {
    short* wreg = Ls + w * 4096;
#pragma unroll
    for (int half = 0; half < 2; ++half) {
#pragma unroll
      for (int ni = 0; ni < 4; ++ni) {
        float bvv = bias ? loadf(bias, n0 + wn * 64 + ni * 16 + l16, f32) : 0.0f;
#pragma unroll
        for (int mi2 = 0; mi2 < 4; ++mi2)
#pragma unroll
          for (int r = 0; r < 4; ++r)
            wreg[(mi2 * 16 + qg * 4 + r) * 64 + ni * 16 + l16] =
                f2b(acc[half * 4 + mi2][ni][r] + bvv);
      }
      asm volatile("s_waitcnt lgkmcnt(0)" ::: "memory");
#pragma unroll
      for (int j = 0; j < 8; ++j) {
        int row = j * 8 + (lane >> 3);
        int col = (lane & 7) * 8;
        short8 v = *(const short8*)(wreg + row * 64 + col);
        *(short8*)((short*)C + (size_t)(crow0 + wm * 128 + half * 64 + row) * N +
                   n0 + wn * 64 + col) = v;
      }
      asm volatile("s_waitcnt lgkmcnt(0)" ::: "memory");
    }
  } else {
    float* wregf = (float*)(Ls) + w * 2048;
#pragma unroll
    for (int half = 0; half < 2; ++half) {
#pragma unroll
      for (int ch = 0; ch < 2; ++ch) {
#pragma unroll
        for (int nh = 0; nh < 2; ++nh) {
          int ni = ch * 2 + nh;
          float bvv = bias ? loadf(bias, n0 + wn * 64 + ni * 16 + l16, f32) : 0.0f;
#pragma unroll
          for (int mi2 = 0; mi2 < 4; ++mi2)
#pragma unroll
            for (int r = 0; r < 4; ++r)
              wregf[(mi2 * 16 + qg * 4 + r) * 32 + nh * 16 + l16] =
                  acc[half * 4 + mi2][ni][r] + bvv;
        }
        asm volatile("s_waitcnt lgkmcnt(0)" ::: "memory");
#pragma unroll
        for (int j = 0; j < 8; ++j) {
          int row = j * 8 + (lane >> 3);
          int c4 = (lane & 7) * 4;
          float4 v = *(const float4*)(wregf + row * 32 + c4);
          *(float4*)((float*)C + (size_t)(crow0 + wm * 128 + half * 64 + row) * N +
                     n0 + wn * 64 + ch * 32 + c4) = v;
        }
        asm volatile("s_waitcnt lgkmcnt(0)" ::: "memory");
      }
    }
  }
#undef ASB
#undef BSB
}

// ---------- GEMM v10 variant (out-proj): 128x128 tile, 3 blocks/CU.
__global__ __launch_bounds__(256, 3)
void gemm_bf128(const short* __restrict__ A,
                const short* __restrict__ BTa, const void* __restrict__ biasa,
                int a0a, int c0a, int nYa,
                const short* __restrict__ BTb, const void* __restrict__ biasb,
                int a0b, int c0b,
                void* __restrict__ C, int N, int K,
                const int* __restrict__ dflag, int cOut) {
  __shared__ short Ls[6 * 128 * 32];           // 48 KB
#define ASB(b) (Ls + (b) * 4096)
#define BSB(b) (Ls + (3 + (b)) * 4096)
  const bool f32 = (*dflag != 0);
  const bool c32 = cOut && f32;
  const int bx = blockIdx.x;
  const int y = blockIdx.y;
  const short* BT; const void* bias; int arow0, crow0;
  if (y < nYa) { BT = BTa; bias = biasa; arow0 = a0a + (y << 7); crow0 = c0a + (y << 7); }
  else { int my = y - nYa; BT = BTb; bias = biasb; arow0 = a0b + (my << 7); crow0 = c0b + (my << 7); }
  const int tid = threadIdx.x;
  const int lane = tid & 63, w = tid >> 6;
  const int wm = w & 1, wn = w >> 1;
  const int qg = lane >> 4, l16 = lane & 15;
  const int n0 = bx << 7;
  const int garow = lane >> 2;
  const int gcir = lane & 3;
  const int nk = K >> 5;
  const int swz = (gcir ^ (garow & 3) ^ (garow >> 2)) << 3;
  const short* Abase = A + (size_t)(arow0 + w * 32 + garow) * K + swz;
  const short* Bbase = BT + (size_t)(n0 + w * 32 + garow) * K + swz;
  const int rswz = (l16 & 3) ^ (l16 >> 2);

  floatx4 acc[4][4];
#pragma unroll
  for (int i = 0; i < 4; ++i)
#pragma unroll
    for (int j = 0; j < 4; ++j) acc[i][j] = (floatx4){0.f, 0.f, 0.f, 0.f};

  auto STAGE = [&](int buf, int k0) {
#pragma unroll
    for (int j = 0; j < 2; ++j) {
      gload16(Abase + (size_t)j * 16 * K + k0, ASB(buf) + ((w * 2 + j) << 9));
      gload16(Bbase + (size_t)j * 16 * K + k0, BSB(buf) + ((w * 2 + j) << 9));
    }
  };

  STAGE(0, 0);
  if (nk > 1) STAGE(1, 32);

  int cb = 0;
  for (int t = 0; t < nk; ++t) {
    if (t + 1 < nk) {
      asm volatile("s_waitcnt vmcnt(4) lgkmcnt(0)" ::: "memory");
    } else {
      asm volatile("s_waitcnt vmcnt(0) lgkmcnt(0)" ::: "memory");
    }
    __builtin_amdgcn_s_barrier();
    if (t + 2 < nk) {
      int sb = (cb == 0) ? 2 : cb - 1;
      STAGE(sb, (t + 2) << 5);
    }
    short8 a[4], b[4];
#pragma unroll
    for (int mi = 0; mi < 4; ++mi) {
      int ra = wm * 64 + mi * 16 + l16;
      a[mi] = *(const short8*)(ASB(cb) + (ra << 5) + ((qg ^ rswz) << 3));
    }
#pragma unroll
    for (int ni = 0; ni < 4; ++ni) {
      int n = wn * 64 + ni * 16 + l16;
      b[ni] = *(const short8*)(BSB(cb) + (n << 5) + ((qg ^ rswz) << 3));
    }
    __builtin_amdgcn_s_setprio(1);
#pragma unroll
    for (int ni = 0; ni < 4; ++ni)
#pragma unroll
      for (int mi = 0; mi < 4; ++mi)
        acc[mi][ni] = __builtin_amdgcn_mfma_f32_16x16x32_bf16(a[mi], b[ni], acc[mi][ni], 0, 0, 0);
    __builtin_amdgcn_s_setprio(0);
    cb = (cb == 2) ? 0 : cb + 1;
  }
  __builtin_amdgcn_s_barrier();
  if (!c32) {
    short* wreg = Ls + w * 4096;
#pragma unroll
    for (int ni = 0; ni < 4; ++ni) {
      float bvv = bias ? loadf(bias, n0 + wn * 64 + ni * 16 + l16, f32) : 0.0f;
#pragma unroll
      for (int mi = 0; mi < 4; ++mi)
#pragma unroll
        for (int r = 0; r < 4; ++r)
          wreg[(mi * 16 + qg * 4 + r) * 64 + ni * 16 + l16] = f2b(acc[mi][ni][r] + bvv);
    }
    asm volatile("s_waitcnt lgkmcnt(0)" ::: "memory");
#pragma unroll
    for (int j = 0; j < 8; ++j) {
      int row = j * 8 + (lane >> 3);
      int col = (lane & 7) * 8;
      short8 v = *(const short8*)(wreg + row * 64 + col);
      *(short8*)((short*)C + (size_t)(crow0 + wm * 64 + row) * N + n0 + wn * 64 + col) = v;
    }
  } else {
    float* wregf = (float*)(Ls) + w * 2048;
#pragma unroll
    for (int half = 0; half < 2; ++half) {
#pragma unroll
      for (int nh = 0; nh < 2; ++nh) {
        int ni = half * 2 + nh;
        float bvv = bias ? loadf(bias, n0 + wn * 64 + ni * 16 + l16, f32) : 0.0f;
#pragma unroll
        for (int mi = 0; mi < 4; ++mi)
#pragma unroll
          for (int r = 0; r < 4; ++r)
            wregf[(mi * 16 + qg * 4 + r) * 32 + nh * 16 + l16] = acc[mi][ni][r] + bvv;
      }
      asm volatile("s_waitcnt lgkmcnt(0)" ::: "memory");
#pragma unroll
      for (int j = 0; j < 8; ++j) {
        int row = j * 8 + (lane >> 3);
        int c4 = (lane & 7) * 4;
        float4 v = *(const float4*)(wregf + row * 32 + c4);
        *(float4*)((float*)C + (size_t)(crow0 + wm * 64 + row) * N + n0 + wn * 64 + half * 32 + c4) = v;
      }
      asm volatile("s_waitcnt lgkmcnt(0)" ::: "memory");
    }
  }
#undef ASB
#undef BSB
}

// ---------- RMSNorm + RoPE: one wave per head; q scaled by rsqrt(128)*log2(e).
__global__ __launch_bounds__(512)
void norm_rope(short* __restrict__ qkv, const int* __restrict__ ids,
               const void* __restrict__ nqw, const void* __restrict__ nkw,
               const void* __restrict__ naqw, const void* __restrict__ nakw,
               const int* __restrict__ dflag) {
  const bool f32 = (*dflag != 0);
  const int t = blockIdx.x, wv = threadIdx.x >> 6, lane = threadIdx.x & 63;
  const bool txt = t < 512;
  int p = lane, axis; float expo;
  if (p < 8)       { axis = 0; expo = (float)(2 * p) * (1.0f / 16.0f); }
  else if (p < 36) { axis = 1; expo = (float)(2 * (p - 8)) * (1.0f / 56.0f); }
  else             { axis = 2; expo = (float)(2 * (p - 36)) * (1.0f / 56.0f); }
  float freq = __expf(-expo * 9.210340371976184f);
  float ang = (float)ids[t * 3 + axis] * freq;
  float s, c; sincosf(ang, &s, &c);
  const void* qw = txt ? naqw : nqw;
  const void* kw = txt ? nakw : nkw;
  float w0q = loadf(qw, 2 * lane, f32), w1q = loadf(qw, 2 * lane + 1, f32);
  float w0k = loadf(kw, 2 * lane, f32), w1k = loadf(kw, 2 * lane + 1, f32);
  const float QS = 0.08838834764831845f * 1.4426950408889634f;
#pragma unroll
  for (int i = 0; i < 3; ++i) {
    int h = wv + 8 * i;
    short* qp = qkv + (size_t)t * 9216 + h * 128 + 2 * lane;
    short* kp = qp + 3072;
    union { unsigned u; short sh[2]; } qv, kv;
    qv.u = *(const unsigned*)qp;
    kv.u = *(const unsigned*)kp;
    float q0 = b2f(qv.sh[0]), q1 = b2f(qv.sh[1]);
    float k0 = b2f(kv.sh[0]), k1 = b2f(kv.sh[1]);
    float sq = q0 * q0 + q1 * q1, sk = k0 * k0 + k1 * k1;
#pragma unroll
    for (int o = 1; o < 64; o <<= 1) { sq += __shfl_xor(sq, o); sk += __shfl_xor(sk, o); }
    float rq = rsqrtf(sq * (1.0f / 128.0f) + 1e-5f);
    float rk = rsqrtf(sk * (1.0f / 128.0f) + 1e-5f);
    float qn0 = q0 * rq * w0q, qn1 = q1 * rq * w1q;
    float kn0 = k0 * rk * w0k, kn1 = k1 * rk * w1k;
    float qo0 = qn0 * c - qn1 * s, qo1 = qn1 * c + qn0 * s;
    float ko0 = kn0 * c - kn1 * s, ko1 = kn1 * c + kn0 * s;
    union { unsigned u; short sh[2]; } qo, ko;
    qo.sh[0] = f2b(qo0 * QS);
    qo.sh[1] = f2b(qo1 * QS);
    ko.sh[0] = f2b(ko0); ko.sh[1] = f2b(ko1);
    *(unsigned*)qp = qo.u;
    *(unsigned*)kp = ko.u;
  }
}

// ---------- flash attention v10: Q-tile 128, KB=128, 2 blocks/CU.
// R17 diagnosis: v9 @ 1 block/CU has ~10K cyc/iter of bare phase-serialization
// stalls. v8's regression causes (2x softmax freq from KB=64; conflicts) are
// avoided: KB stays 128 (per-row softmax work == v9). LDS squeezed to 72 KB:
// Q direct-to-regs (no Q staging), P never materialized full-size — held as 16
// cvt_pk u32 regs, spilled per-kc into a 1KB/wave chunk buffer inside the PV
// loop (wave-private, no barriers). Per-32-key k-order perm t'=2(t&15)+(t>>4)
// applied identically to P pack and V^T commit (agreement verified symbolically).
// grid 480 (24 heads x 20 q-tiles), 1.875 blocks/CU avg.
__global__ __launch_bounds__(512, 2)
void attn_fa(const short* __restrict__ qkv, short* __restrict__ attn) {
  __shared__ short KVs[2][128 * 128];   // 64 KB: K tiles; V^T overwrites in place
  __shared__ short Pw[8][512];          // 8 KB: per-wave P chunk (16 rows x 32 keys)
  const int wgid = blockIdx.x;
  const int xcd = wgid & 7, slot = wgid >> 3;   // 60 slots/XCD
  const int h = xcd * 3 + slot / 20;            // 3 heads per XCD (L2-resident K/V)
  const int qt = slot % 20;
  const int tid = threadIdx.x, lane = tid & 63, w = tid >> 6;  // 8 waves
  const int qg = lane >> 4, l16 = lane & 15;
  const int lr = lane >> 4, lc = lane & 15;
  const int q0 = qt << 7;
  const int sc = tid & 15;
  const int srow5 = (tid >> 4) & 15, half = tid >> 8;

  const short* Qg  = qkv + (size_t)q0 * 9216 + h * 128;
  const short* Kg0 = qkv + 3072 + h * 128;
  const short* Vg0 = qkv + 6144 + h * 128;

  // ---- prologue: K(0) gloads FIRST (drained by vmcnt(8)), then Q regs, V regs
#pragma unroll
  for (int j = 0; j < 4; ++j) {
    int row = j * 32 + w * 4 + lr;
    gload16(Kg0 + (size_t)row * 9216 + ((lc ^ (row & 7)) << 3),
            &KVs[0][(j * 32 + w * 4) * 128]);
  }
  short8 aq[4];
#pragma unroll
  for (int kc = 0; kc < 4; ++kc)
    aq[kc] = *(const short8*)(Qg + (size_t)(w * 16 + l16) * 9216 + kc * 32 + qg * 8);
  short8 vr[4];
#pragma unroll
  for (int j = 0; j < 4; ++j) {
    int row = half * 64 + j * 16 + srow5;
    vr[j] = *(const short8*)(Vg0 + (size_t)row * 9216 + sc * 8);
  }
  asm volatile("s_waitcnt vmcnt(8) lgkmcnt(0)" ::: "memory");  // K(0) done; Q,V in flight
  __builtin_amdgcn_s_barrier();

  floatx4 acc_o[8];
#pragma unroll
  for (int nd = 0; nd < 8; ++nd) acc_o[nd] = (floatx4){0.f, 0.f, 0.f, 0.f};
  float m_i[4], l_i[4];
#pragma unroll
  for (int r = 0; r < 4; ++r) { m_i[r] = -1e30f; l_i[r] = 0.0f; }

  for (int kt = 0; kt < 20; ++kt) {
    const int cb = kt & 1;
    asm volatile("s_waitcnt vmcnt(4) lgkmcnt(0)" ::: "memory");  // K(kt) landed; V(kt) in flight
    __builtin_amdgcn_s_barrier();
    if (kt < 19) {
      const short* Kg = qkv + ((size_t)(kt + 1) * 128) * 9216 + 3072 + h * 128;
#pragma unroll
      for (int j = 0; j < 4; ++j) {
        int row = j * 32 + w * 4 + lr;
        gload16(Kg + (size_t)row * 9216 + ((lc ^ (row & 7)) << 3),
                &KVs[1 - cb][(j * 32 + w * 4) * 128]);
      }
    }
    // ---- QK^T: 16 q-rows x 128 keys (scores in log2 domain via q-scale)
    floatx4 acc_s[8];
#pragma unroll
    for (int ni = 0; ni < 8; ++ni) acc_s[ni] = (floatx4){0.f, 0.f, 0.f, 0.f};
    __builtin_amdgcn_s_setprio(1);
#pragma unroll
    for (int kc = 0; kc < 4; ++kc) {
#pragma unroll
      for (int ni = 0; ni < 8; ++ni) {
        int row = ni * 16 + l16;
        short8 b = *(const short8*)(&KVs[cb][row * 128 + (((kc * 4 + qg) ^ (row & 7)) << 3)]);
        acc_s[ni] = __builtin_amdgcn_mfma_f32_16x16x32_bf16(aq[kc], b, acc_s[ni], 0, 0, 0);
      }
    }
    __builtin_amdgcn_s_setprio(0);
    // ---- online softmax, exp2 domain, defer-rescale (T13)
    float mxv[4];
    bool need = false;
#pragma unroll
    for (int r = 0; r < 4; ++r) {
      float mx = acc_s[0][r];
#pragma unroll
      for (int ni = 1; ni < 8; ++ni) mx = fmaxf(mx, acc_s[ni][r]);
      mx = fmaxf(mx, __shfl_xor(mx, 1));
      mx = fmaxf(mx, __shfl_xor(mx, 2));
      mx = fmaxf(mx, __shfl_xor(mx, 4));
      mx = fmaxf(mx, __shfl_xor(mx, 8));
      mxv[r] = mx;
      need = need || (mx > m_i[r] + 8.0f);
    }
    if (__ballot(need)) {
#pragma unroll
      for (int r = 0; r < 4; ++r) {
        float mn = fmaxf(m_i[r], mxv[r]);
        float al = __builtin_amdgcn_exp2f(m_i[r] - mn);
        m_i[r] = mn;
        l_i[r] *= al;
#pragma unroll
        for (int nd = 0; nd < 8; ++nd) acc_o[nd][r] *= al;
      }
    }
    // pkr[r][kc]: bf16x2 of (pv[2kc], pv[2kc+1]) — P for chunk kc, in-chunk
    // t' = 2*l16 (+1). Held in regs until the PV loop spills per-kc to Pw.
    unsigned pkr[4][4];
#pragma unroll
    for (int r = 0; r < 4; ++r) {
      float pv[8];
      float rs = 0.f;
#pragma unroll
      for (int ni = 0; ni < 8; ++ni) {
        pv[ni] = __builtin_amdgcn_exp2f(acc_s[ni][r] - m_i[r]);
        rs += pv[ni];
      }
#pragma unroll
      for (int kc = 0; kc < 4; ++kc) pkr[r][kc] = cvtpk(pv[2 * kc], pv[2 * kc + 1]);
      rs += __shfl_xor(rs, 1); rs += __shfl_xor(rs, 2);
      rs += __shfl_xor(rs, 4); rs += __shfl_xor(rs, 8);
      l_i[r] += rs;
    }
    asm volatile("s_waitcnt lgkmcnt(0)" ::: "memory");
    __builtin_amdgcn_s_barrier();   // QK^T reads of KVs[cb] done
    // ---- commit V^T(kt) into KVs[cb]: token r -> chunk r>>5, in-chunk
    // t' = 2*(r&15) + ((r>>4)&1). Thread holds tokens half*64+j*16+srow5:
    // pairs (j=2jp, 2jp+1) -> chunk 2*half+jp, t' = 2*srow5 (+1) -> one b32.
    // Group g = kc*4 + (t'>>3) stored at g ^ (d&7) ^ ((d>>3)&7).
#pragma unroll
    for (int u = 0; u < 8; ++u) {
      int d = sc * 8 + u;
      int xr = (d & 7) ^ ((d >> 3) & 7);
#pragma unroll
      for (int jp = 0; jp < 2; ++jp) {
        int kcw = 2 * half + jp;
        int g = kcw * 4 + (srow5 >> 2);
        union { unsigned uu; short sh[2]; } pk;
        pk.sh[0] = vr[2 * jp][u]; pk.sh[1] = vr[2 * jp + 1][u];
        *(unsigned*)(&KVs[cb][d * 128 + ((g ^ xr) << 3) + ((2 * srow5) & 7)]) = pk.uu;
      }
    }
    if (kt < 19) {
      const short* Vg = qkv + ((size_t)(kt + 1) * 128) * 9216 + 6144 + h * 128;
#pragma unroll
      for (int j = 0; j < 4; ++j) {
        int row = half * 64 + j * 16 + srow5;
        vr[j] = *(const short8*)(Vg + (size_t)row * 9216 + sc * 8);
      }
    }
    asm volatile("s_waitcnt lgkmcnt(0)" ::: "memory");
    __builtin_amdgcn_s_barrier();
    // ---- PV: per kc spill P chunk to wave-private Pw, read A-frag, 8 MFMA.
    // P layout: row rr (0..15) x col2-unit cu (0..15, 2 shorts each);
    // phys unit = cu ^ ((rr>>2)<<2). Write: rr=qg*4+r, cu=l16. Read: rr=l16,
    // units qg*4..+3 -> contiguous b128 at ((qg ^ (l16>>2))<<3).
    __builtin_amdgcn_s_setprio(1);
#pragma unroll
    for (int kc = 0; kc < 4; ++kc) {
#pragma unroll
      for (int r = 0; r < 4; ++r)
        *(unsigned*)(&Pw[w][(qg * 4 + r) * 32 + ((l16 ^ (qg << 2)) << 1)]) = pkr[r][kc];
      short8 ap = *(const short8*)(&Pw[w][l16 * 32 + ((qg ^ (l16 >> 2)) << 3)]);
#pragma unroll
      for (int nd = 0; nd < 8; ++nd) {
        int d = nd * 16 + l16;
        int chn = (kc * 4 + qg) ^ (d & 7) ^ ((d >> 3) & 7);
        short8 b = *(const short8*)(&KVs[cb][d * 128 + (chn << 3)]);
        acc_o[nd] = __builtin_amdgcn_mfma_f32_16x16x32_bf16(ap, b, acc_o[nd], 0, 0, 0);
      }
    }
    __builtin_amdgcn_s_setprio(0);
  }
  // ---- epilogue: normalize, transpose through KVs (freed), coalesced stores
  asm volatile("s_waitcnt lgkmcnt(0)" ::: "memory");
  __builtin_amdgcn_s_barrier();   // all PV reads done
  short* Es = &KVs[0][0];         // 128 rows x 128 shorts
  float inv[4];
#pragma unroll
  for (int r = 0; r < 4; ++r) inv[r] = 1.0f / l_i[r];
#pragma unroll
  for (int nd = 0; nd < 8; ++nd)
#pragma unroll
    for (int r = 0; r < 4; ++r) {
      int row = w * 16 + qg * 4 + r;
      Es[row * 128 + nd * 16 + l16] = f2b(acc_o[nd][r] * inv[r]);
    }
  asm volatile("s_waitcnt lgkmcnt(0)" ::: "memory");   // wave-private rows
#pragma unroll
  for (int j = 0; j < 4; ++j) {
    int rrow = w * 16 + j * 4 + qg;
    short8 vv = *(const short8*)(Es + rrow * 128 + l16 * 8);
    *(short8*)(attn + (size_t)(q0 + rrow) * 3072 + h * 128 + l16 * 8) = vv;
  }
}

extern "C" void kernel_launch(void* const* d_in, const int* in_sizes, int n_in,
                              void* d_out, int out_size, void* d_ws, size_t ws_size,
                              hipStream_t stream) {
  (void)in_sizes; (void)n_in; (void)out_size;
  const void* hidden    = d_in[0];
  const void* enc       = d_in[1];
  const int*  ids       = (const int*)d_in[2];
  const void* w_qkv     = d_in[3];
  const void* w_add_qkv = d_in[4];
  const void* b_add_qkv = d_in[5];
  const void* w_out     = d_in[6];
  const void* b_out     = d_in[7];
  const void* w_add_out = d_in[8];
  const void* b_add_out = d_in[9];
  const void* nqw  = d_in[10];
  const void* nkw  = d_in[11];
  const void* naqw = d_in[12];
  const void* nakw = d_in[13];

  int*   dflag = (int*)d_ws;
  short* qkv   = (short*)((char*)d_ws + 256);   // [2560][9216] bf16
  short* attnB = qkv + (size_t)2560 * 9216;     // [2560][3072] bf16

  short* pool  = attnB + (size_t)2560 * 3072;
  const long n_hid  = 2048L * 3072;
  const long n_enc  = 512L * 3072;
  const long n_wqkv = 3072L * 9216;
  const long n_wout = 3072L * 3072;
  short* xb   = pool;                    // [2560][3072]
  short* wqb  = xb + n_enc + n_hid;      // w_qkv^T    [9216][3072]
  short* waqb = wqb + n_wqkv;            // w_add_qkv^T[9216][3072]
  short* wob  = waqb + n_wqkv;           // w_out^T    [3072][3072]
  short* waob = wob + n_wout;            // w_add_out^T[3072][3072]
  const size_t REQ = 256 + 2 * ((size_t)2560 * 9216 + (size_t)2560 * 3072 +
                                n_hid + n_enc + 2 * n_wqkv + 2 * n_wout);

  detect_dtype<<<1, 256, 0, stream>>>((const unsigned short*)w_qkv, dflag);

  if (ws_size >= REQ) {
    cvt_bf16_2<<<1024, 256, 0, stream>>>(enc, n_enc / 8, hidden, n_hid / 8, xb, dflag);
    cvt_tw<<<dim3(18432), 256, 0, stream>>>(w_qkv, wqb, w_add_qkv, waqb,
                                            w_out, wob, w_add_out, waob, dflag);

    // merged QKV projection, 256-row tiles: y<2 -> enc (bias), y>=2 -> hidden
    gemm_bf2<<<dim3(72, 10), 256, 0, stream>>>(
        xb, waqb, b_add_qkv, 0, 0, 2, wqb, nullptr, 512, 512,
        qkv, 9216, 3072, dflag, 0);
    norm_rope<<<dim3(2560), 512, 0, stream>>>(qkv, ids, nqw, nkw, naqw, nakw, dflag);
    // attention: 480 blocks = 24 heads x 20 q-tiles of 128, 2 blocks/CU target
    attn_fa<<<dim3(480), 512, 0, stream>>>(qkv, attnB);
    // merged out-proj, 128-row tiles: y<16 img, y>=16 enc
    gemm_bf128<<<dim3(24, 20), 256, 0, stream>>>(
        attnB, wob, b_out, 512, 0, 16, waob, b_add_out, 0, 2048,
        d_out, 3072, 3072, dflag, 1);
  } else {
    gemm_bt<<<dim3(72, 4), 256, 0, stream>>>(enc, 0, w_add_qkv, b_add_qkv, qkv, 0, 9216, 3072, dflag, 1, 0);
    gemm_bt<<<dim3(72, 16), 256, 0, stream>>>(hidden, 0, w_qkv, nullptr, qkv, 512, 9216, 3072, dflag, 1, 0);
    norm_rope<<<dim3(2560), 512, 0, stream>>>(qkv, ids, nqw, nkw, naqw, nakw, dflag);
    attn_fa<<<dim3(480), 512, 0, stream>>>(qkv, attnB);
    gemm_bt<<<dim3(24, 16), 256, 0, stream>>>(attnB, 512, w_out, b_out, d_out, 0, 3072, 3072, dflag, 0, 1);
    gemm_bt<<<dim3(24, 4), 256, 0, stream>>>(attnB, 0, w_add_out, b_add_out, d_out, 2048, 3072, 3072, dflag, 0, 1);
  }
}

// Round 19
// 781.539 us; speedup vs baseline: 1.0146x; 1.0046x over previous
//
#include <hip/hip_runtime.h>

typedef __attribute__((ext_vector_type(8))) short short8;
typedef __attribute__((ext_vector_type(4))) short short4v;
typedef __attribute__((ext_vector_type(4))) float floatx4;

__device__ __forceinline__ float b2f(short b) {
  union { unsigned u; float f; } v; v.u = ((unsigned)(unsigned short)b) << 16; return v.f;
}
__device__ __forceinline__ short f2b(float f) {
  union { float f; unsigned u; } v; v.f = f;
  return (short)((v.u + 0x7fffu + ((v.u >> 16) & 1u)) >> 16);
}
// packed f32x2 -> bf16x2 (RNE), single VOP3 instr
__device__ __forceinline__ unsigned cvtpk(float lo, float hi) {
  unsigned r;
  asm("v_cvt_pk_bf16_f32 %0, %1, %2" : "=v"(r) : "v"(lo), "v"(hi));
  return r;
}
__device__ __forceinline__ float loadf(const void* p, size_t i, bool f32) {
  return f32 ? ((const float*)p)[i] : b2f(((const short*)p)[i]);
}
__device__ __forceinline__ short8 load8(const void* p, size_t i, bool f32) {
  if (f32) {
    const float* fp = (const float*)p + i;
    float4 a = *(const float4*)fp;
    float4 b = *(const float4*)(fp + 4);
    short8 r;
    r[0] = f2b(a.x); r[1] = f2b(a.y); r[2] = f2b(a.z); r[3] = f2b(a.w);
    r[4] = f2b(b.x); r[5] = f2b(b.y); r[6] = f2b(b.z); r[7] = f2b(b.w);
    return r;
  }
  return *(const short8*)((const short*)p + i);
}

// async global->LDS, 16B per lane. LDS dest = wave-uniform base + lane*16.
__device__ __forceinline__ void gload16(const short* g, short* l) {
  __builtin_amdgcn_global_load_lds(
      (const __attribute__((address_space(1))) unsigned int*)g,
      (__attribute__((address_space(3))) unsigned int*)l, 16, 0, 0);
}

// ---------- dtype detector
__global__ void detect_dtype(const unsigned short* __restrict__ w, int* __restrict__ flag) {
  __shared__ int cnt;
  if (threadIdx.x == 0) cnt = 0;
  __syncthreads();
  int bad = 0;
  for (int i = threadIdx.x; i < 4096; i += 256) {
    int e = (w[i] >> 7) & 0xFF;
    if (e >= 0xC8) bad++;
  }
  atomicAdd(&cnt, bad);
  __syncthreads();
  if (threadIdx.x == 0) *flag = (cnt > 64) ? 1 : 0;
}

// ---------- one-time dtype normalization: two sources -> one contiguous dst
__global__ __launch_bounds__(256)
void cvt_bf16_2(const void* __restrict__ srcA, long n8A,
                const void* __restrict__ srcB, long n8B,
                short* __restrict__ dst, const int* __restrict__ dflag) {
  const bool f32 = (*dflag != 0);
  const long n8 = n8A + n8B;
  long stride = (long)gridDim.x * 256;
  for (long i = (long)blockIdx.x * 256 + threadIdx.x; i < n8; i += stride) {
    const void* s; long e;
    if (i < n8A) { s = srcA; e = i * 8; } else { s = srcB; e = (i - n8A) * 8; }
    if (f32) {
      const float* fp = (const float*)s + e;
      float4 a = *(const float4*)fp;
      float4 b = *(const float4*)(fp + 4);
      short8 r;
      r[0] = f2b(a.x); r[1] = f2b(a.y); r[2] = f2b(a.z); r[3] = f2b(a.w);
      r[4] = f2b(b.x); r[5] = f2b(b.y); r[6] = f2b(b.z); r[7] = f2b(b.w);
      *(short8*)(dst + i * 8) = r;
    } else {
      *(short8*)(dst + i * 8) = *(const short8*)((const short*)s + e);
    }
  }
}

// ---------- cvt_tw: all 4 weight transposes in ONE launch (1-D grid decode).
__global__ __launch_bounds__(256)
void cvt_tw(const void* __restrict__ wq, short* __restrict__ wqd,
            const void* __restrict__ waq, short* __restrict__ waqd,
            const void* __restrict__ wo, short* __restrict__ wod,
            const void* __restrict__ wao, short* __restrict__ waod,
            const int* __restrict__ dflag) {
  __shared__ short st[64][72];
  const bool f32 = (*dflag != 0);
  const int K = 3072;
  int b = blockIdx.x;
  const void* src; short* dst; int N, n0, k0;
  if (b < 13824) {
    src = (b < 6912) ? wq : waq;
    dst = (b < 6912) ? wqd : waqd;
    int rem = b % 6912;
    N = 9216; n0 = (rem % 144) << 6; k0 = (rem / 144) << 6;
  } else {
    b -= 13824;
    src = (b < 2304) ? wo : wao;
    dst = (b < 2304) ? wod : waod;
    int rem = b % 2304;
    N = 3072; n0 = (rem % 48) << 6; k0 = (rem / 48) << 6;
  }
  const int c4 = threadIdx.x & 15;
  const int rq = threadIdx.x >> 4;
#pragma unroll
  for (int r = 0; r < 4; ++r) {
    int k = r * 16 + rq;
    int n = c4 * 4;
    short v0, v1, v2, v3;
    if (f32) {
      const float* sp = (const float*)src + (size_t)(k0 + k) * N + n0 + n;
      float4 f = *(const float4*)sp;
      v0 = f2b(f.x); v1 = f2b(f.y); v2 = f2b(f.z); v3 = f2b(f.w);
    } else {
      const short* sp = (const short*)src + (size_t)(k0 + k) * N + n0 + n;
      short4v s = *(const short4v*)sp;
      v0 = s[0]; v1 = s[1]; v2 = s[2]; v3 = s[3];
    }
    st[n + 0][k] = v0; st[n + 1][k] = v1; st[n + 2][k] = v2; st[n + 3][k] = v3;
  }
  __syncthreads();
  const int n = threadIdx.x >> 2;
  const int kc = (threadIdx.x & 3) << 4;
  short8 a = *(const short8*)(&st[n][kc]);
  short8 bb = *(const short8*)(&st[n][kc + 8]);
  short* dp = dst + (size_t)(n0 + n) * K + k0 + kc;
  *(short8*)(dp) = a;
  *(short8*)(dp + 8) = bb;
}

// ---------- OLD GEMM (fallback) ----------
__global__ __launch_bounds__(256, 2)
void gemm_bt(const void* __restrict__ A, int a_row0,
             const void* __restrict__ B, const void* __restrict__ bias,
             void* __restrict__ C, int c_row0, int N, int K,
             const int* __restrict__ dflag, int aIn, int cOut) {
  __shared__ short As[128 * 32];
  __shared__ short Bs[128 * 32];
  const bool f32 = (*dflag != 0);
  const bool a32 = aIn && f32;
  const bool c32 = cOut && f32;
  const int tid = threadIdx.x;
  const int lane = tid & 63, w = tid >> 6;
  const int wm = w & 1, wn = w >> 1;
  const int qg = lane >> 4, l16 = lane & 15;
  const int m0 = blockIdx.y << 7, n0 = blockIdx.x << 7;

  const int arow = tid >> 2, ak = (tid & 3) << 3;
  const int brow = tid >> 4, bc = (tid & 15) << 3;
  const int rot = tid & 15;

  floatx4 acc[4][4];
#pragma unroll
  for (int i = 0; i < 4; ++i)
#pragma unroll
    for (int j = 0; j < 4; ++j) acc[i][j] = (floatx4){0.f, 0.f, 0.f, 0.f};

  for (int k0 = 0; k0 < K; k0 += 32) {
    __syncthreads();
#pragma unroll
    for (int j = 0; j < 2; ++j) {
      short8 av = load8(A, (size_t)(a_row0 + m0 + j * 64 + arow) * K + (k0 + ak), a32);
      *(short8*)(As + (j * 64 + arow) * 32 + ak) = av;
      int kr = j * 16 + brow;
      short8 bv = load8(B, (size_t)(k0 + kr) * N + (n0 + bc), f32);
      int kq = kr >> 3, kj = kr & 7;
#pragma unroll
      for (int s = 0; s < 8; ++s) {
        int u = (s + rot) & 7;
        int n = bc + u;
        Bs[(n << 5) + ((kq ^ (n & 3)) << 3) + kj] = bv[u];
      }
    }
    __syncthreads();
    short8 a[4];
#pragma unroll
    for (int mi = 0; mi < 4; ++mi)
      a[mi] = *(const short8*)(As + (wm * 64 + mi * 16 + l16) * 32 + qg * 8);
#pragma unroll
    for (int ni = 0; ni < 4; ++ni) {
      int n = wn * 64 + ni * 16 + l16;
      short8 b = *(const short8*)(Bs + (n << 5) + ((qg ^ (n & 3)) << 3));
#pragma unroll
      for (int mi = 0; mi < 4; ++mi)
        acc[mi][ni] = __builtin_amdgcn_mfma_f32_16x16x32_bf16(a[mi], b, acc[mi][ni], 0, 0, 0);
    }
  }
#pragma unroll
  for (int ni = 0; ni < 4; ++ni) {
    int col = n0 + wn * 64 + ni * 16 + l16;
    float bv = bias ? loadf(bias, col, f32) : 0.0f;
#pragma unroll
    for (int mi = 0; mi < 4; ++mi) {
      int row = m0 + wm * 64 + mi * 16 + qg * 4;
#pragma unroll
      for (int r = 0; r < 4; ++r) {
        size_t idx = (size_t)(c_row0 + row + r) * N + col;
        float val = acc[mi][ni][r] + bv;
        if (c32) ((float*)C)[idx] = val;
        else     ((short*)C)[idx] = f2b(val);
      }
    }
  }
}

// ---------- GEMM v11 (qkv): 256x128 block tile, 128x64 wave tile, depth-2
// pipeline, single barrier/K-step, counted vmcnt(6), coalesced epilogue.
__global__ __launch_bounds__(256, 2)
void gemm_bf2(const short* __restrict__ A,
              const short* __restrict__ BTa, const void* __restrict__ biasa,
              int a0a, int c0a, int nYa,
              const short* __restrict__ BTb, const void* __restrict__ biasb,
              int a0b, int c0b,
              void* __restrict__ C, int N, int K,
              const int* __restrict__ dflag, int cOut) {
  __shared__ short Ls[3 * 8192 + 3 * 4096];    // 72 KB
#define ASB(b) (Ls + (b) * 8192)
#define BSB(b) (Ls + 24576 + (b) * 4096)
  const bool f32 = (*dflag != 0);
  const bool c32 = cOut && f32;
  const int bx = blockIdx.x;
  const int y = blockIdx.y;
  const short* BT; const void* bias; int arow0, crow0;
  if (y < nYa) { BT = BTa; bias = biasa; arow0 = a0a + (y << 8); crow0 = c0a + (y << 8); }
  else { int my = y - nYa; BT = BTb; bias = biasb; arow0 = a0b + (my << 8); crow0 = c0b + (my << 8); }
  const int tid = threadIdx.x;
  const int lane = tid & 63, w = tid >> 6;
  const int wm = w & 1, wn = w >> 1;
  const int qg = lane >> 4, l16 = lane & 15;
  const int n0 = bx << 7;
  const int garow = lane >> 2;
  const int gcir = lane & 3;
  const int nk = K >> 5;
  const int swz = (gcir ^ (garow & 3) ^ (garow >> 2)) << 3;
  const short* Abase = A + (size_t)(arow0 + w * 64 + garow) * K + swz;
  const short* Bbase = BT + (size_t)(n0 + w * 32 + garow) * K + swz;
  const int rswz = (l16 & 3) ^ (l16 >> 2);

  floatx4 acc[8][4];
#pragma unroll
  for (int i = 0; i < 8; ++i)
#pragma unroll
    for (int j = 0; j < 4; ++j) acc[i][j] = (floatx4){0.f, 0.f, 0.f, 0.f};

  auto STAGE = [&](int buf, int k0) {
#pragma unroll
    for (int j = 0; j < 4; ++j)
      gload16(Abase + (size_t)j * 16 * K + k0, ASB(buf) + ((w * 4 + j) << 9));
#pragma unroll
    for (int j = 0; j < 2; ++j)
      gload16(Bbase + (size_t)j * 16 * K + k0, BSB(buf) + ((w * 2 + j) << 9));
  };

  STAGE(0, 0);
  if (nk > 1) STAGE(1, 32);

  int cb = 0;
  for (int t = 0; t < nk; ++t) {
    if (t + 1 < nk) {
      asm volatile("s_waitcnt vmcnt(6) lgkmcnt(0)" ::: "memory");
    } else {
      asm volatile("s_waitcnt vmcnt(0) lgkmcnt(0)" ::: "memory");
    }
    __builtin_amdgcn_s_barrier();
    if (t + 2 < nk) {
      int sb = (cb == 0) ? 2 : cb - 1;
      STAGE(sb, (t + 2) << 5);
    }
    short8 a[8], b[4];
#pragma unroll
    for (int mi = 0; mi < 8; ++mi) {
      int ra = wm * 128 + mi * 16 + l16;
      a[mi] = *(const short8*)(ASB(cb) + (ra << 5) + ((qg ^ rswz) << 3));
    }
#pragma unroll
    for (int ni = 0; ni < 4; ++ni) {
      int n = wn * 64 + ni * 16 + l16;
      b[ni] = *(const short8*)(BSB(cb) + (n << 5) + ((qg ^ rswz) << 3));
    }
    __builtin_amdgcn_s_setprio(1);
#pragma unroll
    for (int ni = 0; ni < 4; ++ni)
#pragma unroll
      for (int mi = 0; mi < 8; ++mi)
        acc[mi][ni] = __builtin_amdgcn_mfma_f32_16x16x32_bf16(a[mi], b[ni], acc[mi][ni], 0, 0, 0);
    __builtin_amdgcn_s_setprio(0);
    cb = (cb == 2) ? 0 : cb + 1;
  }
  __builtin_amdgcn_s_barrier();
  if (!c32) {
    short* wreg = Ls + w * 4096;
#pragma unroll
    for (int half = 0; half < 2; ++half) {
#pragma unroll
      for (int ni = 0; ni < 4; ++ni) {
        float bvv = bias ? loadf(bias, n0 + wn * 64 + ni * 16 + l16, f32) : 0.0f;
#pragma unroll
        for (int mi2 = 0; mi2 < 4; ++mi2)
#pragma unroll
          for (int r = 0; r < 4; ++r)
            wreg[(mi2 * 16 + qg * 4 + r) * 64 + ni * 16 + l16] =
                f2b(acc[half * 4 + mi2][ni][r] + bvv);
      }
      asm volatile("s_waitcnt lgkmcnt(0)" ::: "memory");
#pragma unroll
      for (int j = 0; j < 8; ++j) {
        int row = j * 8 + (lane >> 3);
        int col = (lane & 7) * 8;
        short8 v = *(const short8*)(wreg + row * 64 + col);
        *(short8*)((short*)C + (size_t)(crow0 + wm * 128 + half * 64 + row) * N +
                   n0 + wn * 64 + col) = v;
      }
      asm volatile("s_waitcnt lgkmcnt(0)" ::: "memory");
    }
  } else {
    float* wregf = (float*)(Ls) + w * 2048;
#pragma unroll
    for (int half = 0; half < 2; ++half) {
#pragma unroll
      for (int ch = 0; ch < 2; ++ch) {
#pragma unroll
        for (int nh = 0; nh < 2; ++nh) {
          int ni = ch * 2 + nh;
          float bvv = bias ? loadf(bias, n0 + wn * 64 + ni * 16 + l16, f32) : 0.0f;
#pragma unroll
          for (int mi2 = 0; mi2 < 4; ++mi2)
#pragma unroll
            for (int r = 0; r < 4; ++r)
              wregf[(mi2 * 16 + qg * 4 + r) * 32 + nh * 16 + l16] =
                  acc[half * 4 + mi2][ni][r] + bvv;
        }
        asm volatile("s_waitcnt lgkmcnt(0)" ::: "memory");
#pragma unroll
        for (int j = 0; j < 8; ++j) {
          int row = j * 8 + (lane >> 3);
          int c4 = (lane & 7) * 4;
          float4 v = *(const float4*)(wregf + row * 32 + c4);
          *(float4*)((float*)C + (size_t)(crow0 + wm * 128 + half * 64 + row) * N +
                     n0 + wn * 64 + ch * 32 + c4) = v;
        }
        asm volatile("s_waitcnt lgkmcnt(0)" ::: "memory");
      }
    }
  }
#undef ASB
#undef BSB
}

// ---------- GEMM v10 variant (out-proj): 128x128 tile, 3 blocks/CU.
__global__ __launch_bounds__(256, 3)
void gemm_bf128(const short* __restrict__ A,
                const short* __restrict__ BTa, const void* __restrict__ biasa,
                int a0a, int c0a, int nYa,
                const short* __restrict__ BTb, const void* __restrict__ biasb,
                int a0b, int c0b,
                void* __restrict__ C, int N, int K,
                const int* __restrict__ dflag, int cOut) {
  __shared__ short Ls[6 * 128 * 32];           // 48 KB
#define ASB(b) (Ls + (b) * 4096)
#define BSB(b) (Ls + (3 + (b)) * 4096)
  const bool f32 = (*dflag != 0);
  const bool c32 = cOut && f32;
  const int bx = blockIdx.x;
  const int y = blockIdx.y;
  const short* BT; const void* bias; int arow0, crow0;
  if (y < nYa) { BT = BTa; bias = biasa; arow0 = a0a + (y << 7); crow0 = c0a + (y << 7); }
  else { int my = y - nYa; BT = BTb; bias = biasb; arow0 = a0b + (my << 7); crow0 = c0b + (my << 7); }
  const int tid = threadIdx.x;
  const int lane = tid & 63, w = tid >> 6;
  const int wm = w & 1, wn = w >> 1;
  const int qg = lane >> 4, l16 = lane & 15;
  const int n0 = bx << 7;
  const int garow = lane >> 2;
  const int gcir = lane & 3;
  const int nk = K >> 5;
  const int swz = (gcir ^ (garow & 3) ^ (garow >> 2)) << 3;
  const short* Abase = A + (size_t)(arow0 + w * 32 + garow) * K + swz;
  const short* Bbase = BT + (size_t)(n0 + w * 32 + garow) * K + swz;
  const int rswz = (l16 & 3) ^ (l16 >> 2);

  floatx4 acc[4][4];
#pragma unroll
  for (int i = 0; i < 4; ++i)
#pragma unroll
    for (int j = 0; j < 4; ++j) acc[i][j] = (floatx4){0.f, 0.f, 0.f, 0.f};

  auto STAGE = [&](int buf, int k0) {
#pragma unroll
    for (int j = 0; j < 2; ++j) {
      gload16(Abase + (size_t)j * 16 * K + k0, ASB(buf) + ((w * 2 + j) << 9));
      gload16(Bbase + (size_t)j * 16 * K + k0, BSB(buf) + ((w * 2 + j) << 9));
    }
  };

  STAGE(0, 0);
  if (nk > 1) STAGE(1, 32);

  int cb = 0;
  for (int t = 0; t < nk; ++t) {
    if (t + 1 < nk) {
      asm volatile("s_waitcnt vmcnt(4) lgkmcnt(0)" ::: "memory");
    } else {
      asm volatile("s_waitcnt vmcnt(0) lgkmcnt(0)" ::: "memory");
    }
    __builtin_amdgcn_s_barrier();
    if (t + 2 < nk) {
      int sb = (cb == 0) ? 2 : cb - 1;
      STAGE(sb, (t + 2) << 5);
    }
    short8 a[4], b[4];
#pragma unroll
    for (int mi = 0; mi < 4; ++mi) {
      int ra = wm * 64 + mi * 16 + l16;
      a[mi] = *(const short8*)(ASB(cb) + (ra << 5) + ((qg ^ rswz) << 3));
    }
#pragma unroll
    for (int ni = 0; ni < 4; ++ni) {
      int n = wn * 64 + ni * 16 + l16;
      b[ni] = *(const short8*)(BSB(cb) + (n << 5) + ((qg ^ rswz) << 3));
    }
    __builtin_amdgcn_s_setprio(1);
#pragma unroll
    for (int ni = 0; ni < 4; ++ni)
#pragma unroll
      for (int mi = 0; mi < 4; ++mi)
        acc[mi][ni] = __builtin_amdgcn_mfma_f32_16x16x32_bf16(a[mi], b[ni], acc[mi][ni], 0, 0, 0);
    __builtin_amdgcn_s_setprio(0);
    cb = (cb == 2) ? 0 : cb + 1;
  }
  __builtin_amdgcn_s_barrier();
  if (!c32) {
    short* wreg = Ls + w * 4096;
#pragma unroll
    for (int ni = 0; ni < 4; ++ni) {
      float bvv = bias ? loadf(bias, n0 + wn * 64 + ni * 16 + l16, f32) : 0.0f;
#pragma unroll
      for (int mi = 0; mi < 4; ++mi)
#pragma unroll
        for (int r = 0; r < 4; ++r)
          wreg[(mi * 16 + qg * 4 + r) * 64 + ni * 16 + l16] = f2b(acc[mi][ni][r] + bvv);
    }
    asm volatile("s_waitcnt lgkmcnt(0)" ::: "memory");
#pragma unroll
    for (int j = 0; j < 8; ++j) {
      int row = j * 8 + (lane >> 3);
      int col = (lane & 7) * 8;
      short8 v = *(const short8*)(wreg + row * 64 + col);
      *(short8*)((short*)C + (size_t)(crow0 + wm * 64 + row) * N + n0 + wn * 64 + col) = v;
    }
  } else {
    float* wregf = (float*)(Ls) + w * 2048;
#pragma unroll
    for (int half = 0; half < 2; ++half) {
#pragma unroll
      for (int nh = 0; nh < 2; ++nh) {
        int ni = half * 2 + nh;
        float bvv = bias ? loadf(bias, n0 + wn * 64 + ni * 16 + l16, f32) : 0.0f;
#pragma unroll
        for (int mi = 0; mi < 4; ++mi)
#pragma unroll
          for (int r = 0; r < 4; ++r)
            wregf[(mi * 16 + qg * 4 + r) * 32 + nh * 16 + l16] = acc[mi][ni][r] + bvv;
      }
      asm volatile("s_waitcnt lgkmcnt(0)" ::: "memory");
#pragma unroll
      for (int j = 0; j < 8; ++j) {
        int row = j * 8 + (lane >> 3);
        int c4 = (lane & 7) * 4;
        float4 v = *(const float4*)(wregf + row * 32 + c4);
        *(float4*)((float*)C + (size_t)(crow0 + wm * 64 + row) * N + n0 + wn * 64 + half * 32 + c4) = v;
      }
      asm volatile("s_waitcnt lgkmcnt(0)" ::: "memory");
    }
  }
#undef ASB
#undef BSB
}

// ---------- RMSNorm + RoPE: one wave per head; q scaled by rsqrt(128)*log2(e).
__global__ __launch_bounds__(512)
void norm_rope(short* __restrict__ qkv, const int* __restrict__ ids,
               const void* __restrict__ nqw, const void* __restrict__ nkw,
               const void* __restrict__ naqw, const void* __restrict__ nakw,
               const int* __restrict__ dflag) {
  const bool f32 = (*dflag != 0);
  const int t = blockIdx.x, wv = threadIdx.x >> 6, lane = threadIdx.x & 63;
  const bool txt = t < 512;
  int p = lane, axis; float expo;
  if (p < 8)       { axis = 0; expo = (float)(2 * p) * (1.0f / 16.0f); }
  else if (p < 36) { axis = 1; expo = (float)(2 * (p - 8)) * (1.0f / 56.0f); }
  else             { axis = 2; expo = (float)(2 * (p - 36)) * (1.0f / 56.0f); }
  float freq = __expf(-expo * 9.210340371976184f);
  float ang = (float)ids[t * 3 + axis] * freq;
  float s, c; sincosf(ang, &s, &c);
  const void* qw = txt ? naqw : nqw;
  const void* kw = txt ? nakw : nkw;
  float w0q = loadf(qw, 2 * lane, f32), w1q = loadf(qw, 2 * lane + 1, f32);
  float w0k = loadf(kw, 2 * lane, f32), w1k = loadf(kw, 2 * lane + 1, f32);
  const float QS = 0.08838834764831845f * 1.4426950408889634f;
#pragma unroll
  for (int i = 0; i < 3; ++i) {
    int h = wv + 8 * i;
    short* qp = qkv + (size_t)t * 9216 + h * 128 + 2 * lane;
    short* kp = qp + 3072;
    union { unsigned u; short sh[2]; } qv, kv;
    qv.u = *(const unsigned*)qp;
    kv.u = *(const unsigned*)kp;
    float q0 = b2f(qv.sh[0]), q1 = b2f(qv.sh[1]);
    float k0 = b2f(kv.sh[0]), k1 = b2f(kv.sh[1]);
    float sq = q0 * q0 + q1 * q1, sk = k0 * k0 + k1 * k1;
#pragma unroll
    for (int o = 1; o < 64; o <<= 1) { sq += __shfl_xor(sq, o); sk += __shfl_xor(sk, o); }
    float rq = rsqrtf(sq * (1.0f / 128.0f) + 1e-5f);
    float rk = rsqrtf(sk * (1.0f / 128.0f) + 1e-5f);
    float qn0 = q0 * rq * w0q, qn1 = q1 * rq * w1q;
    float kn0 = k0 * rk * w0k, kn1 = k1 * rk * w1k;
    float qo0 = qn0 * c - qn1 * s, qo1 = qn1 * c + qn0 * s;
    float ko0 = kn0 * c - kn1 * s, ko1 = kn1 * c + kn0 * s;
    union { unsigned u; short sh[2]; } qo, ko;
    qo.sh[0] = f2b(qo0 * QS);
    qo.sh[1] = f2b(qo1 * QS);
    ko.sh[0] = f2b(ko0); ko.sh[1] = f2b(ko1);
    *(unsigned*)qp = qo.u;
    *(unsigned*)kp = ko.u;
  }
}

// ---------- flash attention v11 = v10 with conflict-free Pw layout.
// R18 evidence: v10's Pw pitch-32 spill had bank = 16(r&1) + (l16^4qg) ->
// 4-way write conflict (SQ_LDS_BANK_CONFLICT 1.14e7 -> 2.60e7). v11: pitch 40
// shorts, NO xor (phys unit = logical unit). Write bank (16qg+20r+l16)%32 ->
// 2-way (free); read base (20*l16+4qg)%32 -> ~2-way. Logical P content is
// byte-identical to v10 (which passed), only the physical layout changes.
__global__ __launch_bounds__(512, 2)
void attn_fa(const short* __restrict__ qkv, short* __restrict__ attn) {
  __shared__ short KVs[2][128 * 128];   // 64 KB: K tiles; V^T overwrites in place
  __shared__ short Pw[8][640];          // 10 KB: per-wave P chunk, 16 rows x pitch 40
  const int wgid = blockIdx.x;
  const int xcd = wgid & 7, slot = wgid >> 3;   // 60 slots/XCD
  const int h = xcd * 3 + slot / 20;            // 3 heads per XCD (L2-resident K/V)
  const int qt = slot % 20;
  const int tid = threadIdx.x, lane = tid & 63, w = tid >> 6;  // 8 waves
  const int qg = lane >> 4, l16 = lane & 15;
  const int lr = lane >> 4, lc = lane & 15;
  const int q0 = qt << 7;
  const int sc = tid & 15;
  const int srow5 = (tid >> 4) & 15, half = tid >> 8;

  const short* Qg  = qkv + (size_t)q0 * 9216 + h * 128;
  const short* Kg0 = qkv + 3072 + h * 128;
  const short* Vg0 = qkv + 6144 + h * 128;

  // ---- prologue: K(0) gloads FIRST (drained by vmcnt(8)), then Q regs, V regs
#pragma unroll
  for (int j = 0; j < 4; ++j) {
    int row = j * 32 + w * 4 + lr;
    gload16(Kg0 + (size_t)row * 9216 + ((lc ^ (row & 7)) << 3),
            &KVs[0][(j * 32 + w * 4) * 128]);
  }
  short8 aq[4];
#pragma unroll
  for (int kc = 0; kc < 4; ++kc)
    aq[kc] = *(const short8*)(Qg + (size_t)(w * 16 + l16) * 9216 + kc * 32 + qg * 8);
  short8 vr[4];
#pragma unroll
  for (int j = 0; j < 4; ++j) {
    int row = half * 64 + j * 16 + srow5;
    vr[j] = *(const short8*)(Vg0 + (size_t)row * 9216 + sc * 8);
  }
  asm volatile("s_waitcnt vmcnt(8) lgkmcnt(0)" ::: "memory");  // K(0) done; Q,V in flight
  __builtin_amdgcn_s_barrier();

  floatx4 acc_o[8];
#pragma unroll
  for (int nd = 0; nd < 8; ++nd) acc_o[nd] = (floatx4){0.f, 0.f, 0.f, 0.f};
  float m_i[4], l_i[4];
#pragma unroll
  for (int r = 0; r < 4; ++r) { m_i[r] = -1e30f; l_i[r] = 0.0f; }

  for (int kt = 0; kt < 20; ++kt) {
    const int cb = kt & 1;
    asm volatile("s_waitcnt vmcnt(4) lgkmcnt(0)" ::: "memory");  // K(kt) landed; V(kt) in flight
    __builtin_amdgcn_s_barrier();
    if (kt < 19) {
      const short* Kg = qkv + ((size_t)(kt + 1) * 128) * 9216 + 3072 + h * 128;
#pragma unroll
      for (int j = 0; j < 4; ++j) {
        int row = j * 32 + w * 4 + lr;
        gload16(Kg + (size_t)row * 9216 + ((lc ^ (row & 7)) << 3),
                &KVs[1 - cb][(j * 32 + w * 4) * 128]);
      }
    }
    // ---- QK^T: 16 q-rows x 128 keys (scores in log2 domain via q-scale)
    floatx4 acc_s[8];
#pragma unroll
    for (int ni = 0; ni < 8; ++ni) acc_s[ni] = (floatx4){0.f, 0.f, 0.f, 0.f};
    __builtin_amdgcn_s_setprio(1);
#pragma unroll
    for (int kc = 0; kc < 4; ++kc) {
#pragma unroll
      for (int ni = 0; ni < 8; ++ni) {
        int row = ni * 16 + l16;
        short8 b = *(const short8*)(&KVs[cb][row * 128 + (((kc * 4 + qg) ^ (row & 7)) << 3)]);
        acc_s[ni] = __builtin_amdgcn_mfma_f32_16x16x32_bf16(aq[kc], b, acc_s[ni], 0, 0, 0);
      }
    }
    __builtin_amdgcn_s_setprio(0);
    // ---- online softmax, exp2 domain, defer-rescale (T13)
    float mxv[4];
    bool need = false;
#pragma unroll
    for (int r = 0; r < 4; ++r) {
      float mx = acc_s[0][r];
#pragma unroll
      for (int ni = 1; ni < 8; ++ni) mx = fmaxf(mx, acc_s[ni][r]);
      mx = fmaxf(mx, __shfl_xor(mx, 1));
      mx = fmaxf(mx, __shfl_xor(mx, 2));
      mx = fmaxf(mx, __shfl_xor(mx, 4));
      mx = fmaxf(mx, __shfl_xor(mx, 8));
      mxv[r] = mx;
      need = need || (mx > m_i[r] + 8.0f);
    }
    if (__ballot(need)) {
#pragma unroll
      for (int r = 0; r < 4; ++r) {
        float mn = fmaxf(m_i[r], mxv[r]);
        float al = __builtin_amdgcn_exp2f(m_i[r] - mn);
        m_i[r] = mn;
        l_i[r] *= al;
#pragma unroll
        for (int nd = 0; nd < 8; ++nd) acc_o[nd][r] *= al;
      }
    }
    // pkr[r][kc]: bf16x2 of (pv[2kc], pv[2kc+1]) — P chunk kc, in-chunk t'=2*l16(+1)
    unsigned pkr[4][4];
#pragma unroll
    for (int r = 0; r < 4; ++r) {
      float pv[8];
      float rs = 0.f;
#pragma unroll
      for (int ni = 0; ni < 8; ++ni) {
        pv[ni] = __builtin_amdgcn_exp2f(acc_s[ni][r] - m_i[r]);
        rs += pv[ni];
      }
#pragma unroll
      for (int kc = 0; kc < 4; ++kc) pkr[r][kc] = cvtpk(pv[2 * kc], pv[2 * kc + 1]);
      rs += __shfl_xor(rs, 1); rs += __shfl_xor(rs, 2);
      rs += __shfl_xor(rs, 4); rs += __shfl_xor(rs, 8);
      l_i[r] += rs;
    }
    asm volatile("s_waitcnt lgkmcnt(0)" ::: "memory");
    __builtin_amdgcn_s_barrier();   // QK^T reads of KVs[cb] done
    // ---- commit V^T(kt) into KVs[cb] (unchanged from v10)
#pragma unroll
    for (int u = 0; u < 8; ++u) {
      int d = sc * 8 + u;
      int xr = (d & 7) ^ ((d >> 3) & 7);
#pragma unroll
      for (int jp = 0; jp < 2; ++jp) {
        int kcw = 2 * half + jp;
        int g = kcw * 4 + (srow5 >> 2);
        union { unsigned uu; short sh[2]; } pk;
        pk.sh[0] = vr[2 * jp][u]; pk.sh[1] = vr[2 * jp + 1][u];
        *(unsigned*)(&KVs[cb][d * 128 + ((g ^ xr) << 3) + ((2 * srow5) & 7)]) = pk.uu;
      }
    }
    if (kt < 19) {
      const short* Vg = qkv + ((size_t)(kt + 1) * 128) * 9216 + 6144 + h * 128;
#pragma unroll
      for (int j = 0; j < 4; ++j) {
        int row = half * 64 + j * 16 + srow5;
        vr[j] = *(const short8*)(Vg + (size_t)row * 9216 + sc * 8);
      }
    }
    asm volatile("s_waitcnt lgkmcnt(0)" ::: "memory");
    __builtin_amdgcn_s_barrier();
    // ---- PV: per kc spill P chunk to wave-private Pw (pitch 40, no xor):
    // write row rr=qg*4+r, unit l16 -> bank 16qg+20r+l16 (2-way).
    // read row l16, units qg*4..+3 contiguous b128 -> base (20*l16+4qg)%32.
    __builtin_amdgcn_s_setprio(1);
#pragma unroll
    for (int kc = 0; kc < 4; ++kc) {
#pragma unroll
      for (int r = 0; r < 4; ++r)
        *(unsigned*)(&Pw[w][(qg * 4 + r) * 40 + (l16 << 1)]) = pkr[r][kc];
      short8 ap = *(const short8*)(&Pw[w][l16 * 40 + (qg << 3)]);
#pragma unroll
      for (int nd = 0; nd < 8; ++nd) {
        int d = nd * 16 + l16;
        int chn = (kc * 4 + qg) ^ (d & 7) ^ ((d >> 3) & 7);
        short8 b = *(const short8*)(&KVs[cb][d * 128 + (chn << 3)]);
        acc_o[nd] = __builtin_amdgcn_mfma_f32_16x16x32_bf16(ap, b, acc_o[nd], 0, 0, 0);
      }
    }
    __builtin_amdgcn_s_setprio(0);
  }
  // ---- epilogue: normalize, transpose through KVs (freed), coalesced stores
  asm volatile("s_waitcnt lgkmcnt(0)" ::: "memory");
  __builtin_amdgcn_s_barrier();   // all PV reads done
  short* Es = &KVs[0][0];         // 128 rows x 128 shorts
  float inv[4];
#pragma unroll
  for (int r = 0; r < 4; ++r) inv[r] = 1.0f / l_i[r];
#pragma unroll
  for (int nd = 0; nd < 8; ++nd)
#pragma unroll
    for (int r = 0; r < 4; ++r) {
      int row = w * 16 + qg * 4 + r;
      Es[row * 128 + nd * 16 + l16] = f2b(acc_o[nd][r] * inv[r]);
    }
  asm volatile("s_waitcnt lgkmcnt(0)" ::: "memory");   // wave-private rows
#pragma unroll
  for (int j = 0; j < 4; ++j) {
    int rrow = w * 16 + j * 4 + qg;
    short8 vv = *(const short8*)(Es + rrow * 128 + l16 * 8);
    *(short8*)(attn + (size_t)(q0 + rrow) * 3072 + h * 128 + l16 * 8) = vv;
  }
}

extern "C" void kernel_launch(void* const* d_in, const int* in_sizes, int n_in,
                              void* d_out, int out_size, void* d_ws, size_t ws_size,
                              hipStream_t stream) {
  (void)in_sizes; (void)n_in; (void)out_size;
  const void* hidden    = d_in[0];
  const void* enc       = d_in[1];
  const int*  ids       = (const int*)d_in[2];
  const void* w_qkv     = d_in[3];
  const void* w_add_qkv = d_in[4];
  const void* b_add_qkv = d_in[5];
  const void* w_out     = d_in[6];
  const void* b_out     = d_in[7];
  const void* w_add_out = d_in[8];
  const void* b_add_out = d_in[9];
  const void* nqw  = d_in[10];
  const void* nkw  = d_in[11];
  const void* naqw = d_in[12];
  const void* nakw = d_in[13];

  int*   dflag = (int*)d_ws;
  short* qkv   = (short*)((char*)d_ws + 256);   // [2560][9216] bf16
  short* attnB = qkv + (size_t)2560 * 9216;     // [2560][3072] bf16

  short* pool  = attnB + (size_t)2560 * 3072;
  const long n_hid  = 2048L * 3072;
  const long n_enc  = 512L * 3072;
  const long n_wqkv = 3072L * 9216;
  const long n_wout = 3072L * 3072;
  short* xb   = pool;                    // [2560][3072]
  short* wqb  = xb + n_enc + n_hid;      // w_qkv^T    [9216][3072]
  short* waqb = wqb + n_wqkv;            // w_add_qkv^T[9216][3072]
  short* wob  = waqb + n_wqkv;           // w_out^T    [3072][3072]
  short* waob = wob + n_wout;            // w_add_out^T[3072][3072]
  const size_t REQ = 256 + 2 * ((size_t)2560 * 9216 + (size_t)2560 * 3072 +
                                n_hid + n_enc + 2 * n_wqkv + 2 * n_wout);

  detect_dtype<<<1, 256, 0, stream>>>((const unsigned short*)w_qkv, dflag);

  if (ws_size >= REQ) {
    cvt_bf16_2<<<1024, 256, 0, stream>>>(enc, n_enc / 8, hidden, n_hid / 8, xb, dflag);
    cvt_tw<<<dim3(18432), 256, 0, stream>>>(w_qkv, wqb, w_add_qkv, waqb,
                                            w_out, wob, w_add_out, waob, dflag);

    // merged QKV projection, 256-row tiles: y<2 -> enc (bias), y>=2 -> hidden
    gemm_bf2<<<dim3(72, 10), 256, 0, stream>>>(
        xb, waqb, b_add_qkv, 0, 0, 2, wqb, nullptr, 512, 512,
        qkv, 9216, 3072, dflag, 0);
    norm_rope<<<dim3(2560), 512, 0, stream>>>(qkv, ids, nqw, nkw, naqw, nakw, dflag);
    // attention: 480 blocks = 24 heads x 20 q-tiles of 128, 2 blocks/CU
    attn_fa<<<dim3(480), 512, 0, stream>>>(qkv, attnB);
    // merged out-proj, 128-row tiles: y<16 img, y>=16 enc
    gemm_bf128<<<dim3(24, 20), 256, 0, stream>>>(
        attnB, wob, b_out, 512, 0, 16, waob, b_add_out, 0, 2048,
        d_out, 3072, 3072, dflag, 1);
  } else {
    gemm_bt<<<dim3(72, 4), 256, 0, stream>>>(enc, 0, w_add_qkv, b_add_qkv, qkv, 0, 9216, 3072, dflag, 1, 0);
    gemm_bt<<<dim3(72, 16), 256, 0, stream>>>(hidden, 0, w_qkv, nullptr, qkv, 512, 9216, 3072, dflag, 1, 0);
    norm_rope<<<dim3(2560), 512, 0, stream>>>(qkv, ids, nqw, nkw, naqw, nakw, dflag);
    attn_fa<<<dim3(480), 512, 0, stream>>>(qkv, attnB);
    gemm_bt<<<dim3(24, 16), 256, 0, stream>>>(attnB, 512, w_out, b_out, d_out, 0, 3072, 3072, dflag, 0, 1);
    gemm_bt<<<dim3(24, 4), 256, 0, stream>>>(attnB, 0, w_add_out, b_add_out, d_out, 2048, 3072, 3072, dflag, 0, 1);
  }
}